// Round 2
// baseline (806.596 us; speedup 1.0000x reference)
//
#include <hip/hip_runtime.h>
#include <hip/hip_bf16.h>
#include <cstdint>

typedef unsigned short u16;
typedef unsigned int u32;
typedef unsigned long long u64;
typedef __bf16 bf16x8 __attribute__((ext_vector_type(8)));
typedef float f32x4 __attribute__((ext_vector_type(4)));
typedef u16 u16x8 __attribute__((ext_vector_type(8)));

// ---------- helpers ----------
__device__ __forceinline__ u16 f2b(float f) {          // fp32 -> bf16 RNE
    unsigned int u = __float_as_uint(f);
    u += 0x7fffu + ((u >> 16) & 1u);
    return (u16)(u >> 16);
}
__device__ __forceinline__ float b2f(u16 h) {
    return __uint_as_float(((unsigned int)h) << 16);
}
__device__ __forceinline__ void async_cp16(void* lds, const void* g) {
    __builtin_amdgcn_global_load_lds((const __attribute__((address_space(1))) void*)g,
                                     (__attribute__((address_space(3))) void*)lds, 16, 0, 0);
}
// monotone unsigned mapping of float bits (order-preserving, EXACT)
__device__ __forceinline__ u32 fmono(float f) {
    u32 u = __float_as_uint(f);
    return u ^ (((u32)((int)u >> 31)) | 0x80000000u);
}
__device__ __forceinline__ u64 shfl_xor_u64(u64 v, int mask) {
    u32 lo = (u32)v, hi = (u32)(v >> 32);
    lo = (u32)__shfl_xor((int)lo, mask);
    hi = (u32)__shfl_xor((int)hi, mask);
    return ((u64)hi << 32) | lo;
}
// insert exact key into descending top-3 (keys unique: idx field breaks ties)
__device__ __forceinline__ void ins3(u64 k, u64& k0, u64& k1, u64& k2) {
    bool c0 = k > k0, c1 = k > k1, c2 = k > k2;
    k2 = c1 ? k1 : (c2 ? k : k2);
    k1 = c0 ? k0 : (c1 ? k : k1);
    k0 = c0 ? k : k0;
}
// padded pk index: one float4 pad every 64 entries (chunk groups on distinct banks)
__device__ __forceinline__ int pkix(int i) { return i + (i >> 6); }

// ================= prep kernel: three_nn FIRST, then cvt + transposes =================
#define NB_NN  1024
#define NB_CVT 160
#define NB_T2  512
#define NB_T1  1024

__global__ __launch_bounds__(256, 6) void prep_kernel(const float* __restrict__ w1,
                                                      const float* __restrict__ w2,
                                                      u16* __restrict__ wb,
                                                      const float* __restrict__ feature2,
                                                      u16* __restrict__ f2t,
                                                      const float* __restrict__ feature1,
                                                      u16* __restrict__ f1t,
                                                      const float* __restrict__ pos1,
                                                      const float* __restrict__ pos2,
                                                      int* __restrict__ idx_out,
                                                      float* __restrict__ w_out) {
    __shared__ __align__(16) char smem[19712];   // 16640 pk-half + 3072 warr
    int bi = blockIdx.x;
    int tid = threadIdx.x;

    if (bi >= NB_NN) {
        int ci = bi - NB_NN;
        if (ci < NB_CVT) {
            int i = ci * 256 + tid;
            if (i < 40960) {
                const float* src = (i < 24576) ? w1 : w2;
                int k = (i < 24576) ? i : (i - 24576);
                float4 v = *(const float4*)&src[(size_t)k * 4];
                ushort4 o;
                o.x = f2b(v.x); o.y = f2b(v.y); o.z = f2b(v.z); o.w = f2b(v.w);
                *(ushort4*)&wb[(size_t)i * 4] = o;
            }
            return;
        }
        // ---- transpose [B][C][S] -> [B][S][C] bf16 ----
        float (*t)[65] = (float (*)[65])smem;
        const float* in; u16* out; int C, S, s0, c0, b;
        if (ci < NB_CVT + NB_T2) {
            int lin = ci - NB_CVT;
            C = 256; S = 2048; in = feature2; out = f2t;
            s0 = (lin & 31) * 64; c0 = ((lin >> 5) & 3) * 64; b = lin >> 7;
        } else {
            int lin = ci - NB_CVT - NB_T2;
            C = 128; S = 8192; in = feature1; out = f1t;
            s0 = (lin & 127) * 64; c0 = ((lin >> 7) & 1) * 64; b = lin >> 8;
        }
        const float* ib = in + (size_t)b * C * S;
        u16* ob = out + (size_t)b * S * C;
        int col = tid & 63, r0 = tid >> 6;
#pragma unroll
        for (int p = 0; p < 16; ++p) {
            int c = p * 4 + r0;
            t[c][col] = ib[(size_t)(c0 + c) * S + s0 + col];
        }
        __syncthreads();
#pragma unroll
        for (int p = 0; p < 16; ++p) {
            int s = p * 4 + r0;
            ob[(size_t)(s0 + s) * C + c0 + col] = f2b(t[col][s]);
        }
        return;
    }

    // ---- three_nn: 32 queries/block; thread handles queries p, p+16 ----
    float4* pk = (float4*)smem;                          // padded: 1040 float4 = 16640 B
    u64* warr = (u64*)(smem + 16640);                    // [4 waves][16 p][2 t][3]
    int j0 = bi * 32;
    int b = j0 >> 13;
    const float* p2 = pos2 + (size_t)b * 3 * 2048;
    int p = tid & 15, ck = tid >> 4;
    int wv = tid >> 6, lane = tid & 63;
    const float* p1 = pos1 + (size_t)b * 3 * 8192;
    float qx[2], qy[2], qz[2];
#pragma unroll
    for (int t = 0; t < 2; ++t) {
        int n = (j0 & 8191) + p + t * 16;
        qx[t] = p1[n]; qy[t] = p1[8192 + n]; qz[t] = p1[16384 + n];
    }
    u64 key[2][3];
#pragma unroll
    for (int t = 0; t < 2; ++t) { key[t][0] = 0; key[t][1] = 0; key[t][2] = 0; }

    for (int half = 0; half < 2; ++half) {
        int hbase = half * 1024;
        for (int i = tid; i < 1024; i += 256) {
            int s = hbase + i;
            float x = p2[s], y = p2[2048 + s], z = p2[4096 + s];
            pk[pkix(i)] = make_float4(x, y, z, -0.5f * (x * x + y * y + z * z));
        }
        __syncthreads();

        float g[2][3]; int id[2][3];
#pragma unroll
        for (int t = 0; t < 2; ++t) {
            g[t][0] = -3.4e38f; g[t][1] = -3.4e38f; g[t][2] = -3.4e38f;
            id[t][0] = 0; id[t][1] = 0; id[t][2] = 0;
        }
        int sb = ck * 64;
        const float4* pc = pk + pkix(sb);
#pragma unroll 2
        for (int it = 0; it < 64; ++it) {
            float4 cd = pc[it];
            int s = sb + it;
#pragma unroll
            for (int t = 0; t < 2; ++t) {
                float tv = fmaf(qx[t], cd.x, fmaf(qy[t], cd.y, fmaf(qz[t], cd.z, cd.w)));
                bool c0 = tv > g[t][0], c1 = tv > g[t][1], c2 = tv > g[t][2];
                // value maintenance via max/med3 (3 ops, exact same results incl. ties)
                float o0 = g[t][0], o1 = g[t][1];
                g[t][2] = __builtin_amdgcn_fmed3f(tv, o1, g[t][2]);
                g[t][1] = __builtin_amdgcn_fmed3f(tv, o0, o1);
                g[t][0] = fmaxf(o0, tv);
                id[t][2] = c1 ? id[t][1] : (c2 ? s : id[t][2]);
                id[t][1] = c0 ? id[t][0] : (c1 ? s : id[t][1]);
                id[t][0] = c0 ? s : id[t][0];
            }
        }
        __syncthreads();   // reads done before next half restages

#pragma unroll
        for (int t = 0; t < 2; ++t) {
#pragma unroll
            for (int r = 0; r < 3; ++r)
                ins3(((u64)fmono(g[t][r]) << 32) | (u64)(2047 - (hbase + id[t][r])),
                     key[t][0], key[t][1], key[t][2]);
        }
    }

    // in-wave merge across the 4 chunk-groups (lane>>4)
#pragma unroll
    for (int mask = 16; mask <= 32; mask <<= 1) {
#pragma unroll
        for (int t = 0; t < 2; ++t) {
            u64 m0 = shfl_xor_u64(key[t][0], mask);
            u64 m1 = shfl_xor_u64(key[t][1], mask);
            u64 m2 = shfl_xor_u64(key[t][2], mask);
            ins3(m0, key[t][0], key[t][1], key[t][2]);
            ins3(m1, key[t][0], key[t][1], key[t][2]);
            ins3(m2, key[t][0], key[t][1], key[t][2]);
        }
    }
    if (lane < 16) {
        u64* wr = &warr[(wv * 16 + p) * 6];
#pragma unroll
        for (int t = 0; t < 2; ++t) {
            wr[t * 3 + 0] = key[t][0]; wr[t * 3 + 1] = key[t][1]; wr[t * 3 + 2] = key[t][2];
        }
    }
    __syncthreads();
    if (tid < 32) {
        int pp = tid & 15, t = tid >> 4;
        const u64* w0 = &warr[pp * 6 + t * 3];
        u64 k0 = w0[0], k1 = w0[1], k2 = w0[2];
#pragma unroll
        for (int w = 1; w < 4; ++w) {
            const u64* wr = &warr[(w * 16 + pp) * 6 + t * 3];
            ins3(wr[0], k0, k1, k2);
            ins3(wr[1], k0, k1, k2);
            ins3(wr[2], k0, k1, k2);
        }
        int s0 = 2047 - (int)(k0 & 0xFFFFFFFFu);
        int s1 = 2047 - (int)(k1 & 0xFFFFFFFFu);
        int s2 = 2047 - (int)(k2 & 0xFFFFFFFFu);
        int j = j0 + pp + t * 16;
        int n = j & 8191;
        float x1 = p1[n], y1 = p1[8192 + n], z1 = p1[16384 + n];
        float n1 = x1 * x1 + y1 * y1 + z1 * z1;
        float X0 = p2[s0], Y0 = p2[2048 + s0], Z0 = p2[4096 + s0];
        float X1 = p2[s1], Y1v = p2[2048 + s1], Z1 = p2[4096 + s1];
        float X2 = p2[s2], Y2v = p2[2048 + s2], Z2 = p2[4096 + s2];
        float t0 = x1 * X0 + y1 * Y0 + z1 * Z0 - 0.5f * (X0 * X0 + Y0 * Y0 + Z0 * Z0);
        float t1 = x1 * X1 + y1 * Y1v + z1 * Z1 - 0.5f * (X1 * X1 + Y1v * Y1v + Z1 * Z1);
        float t2 = x1 * X2 + y1 * Y2v + z1 * Z2 - 0.5f * (X2 * X2 + Y2v * Y2v + Z2 * Z2);
        float d0 = fmaxf(fmaf(-2.f, t0, n1), 1e-10f);
        float d1 = fmaxf(fmaf(-2.f, t1, n1), 1e-10f);
        float d2 = fmaxf(fmaf(-2.f, t2, n1), 1e-10f);
        float w0v = 1.f / d0, w1v = 1.f / d1, w2v = 1.f / d2;
        float inv = 1.f / (w0v + w1v + w2v);
        idx_out[j * 3] = s0; idx_out[j * 3 + 1] = s1; idx_out[j * 3 + 2] = s2;
        w_out[j * 3] = w0v * inv; w_out[j * 3 + 1] = w1v * inv; w_out[j * 3 + 2] = w2v * inv;
    }
}

// ---------- interp: gather 3 rows of F2T, weighted sum -> bf16 [32768][256] ----------
__global__ __launch_bounds__(256, 8) void interp_kernel(const u16* __restrict__ f2t,
                                                        const int* __restrict__ idx,
                                                        const float* __restrict__ wgt,
                                                        u16* __restrict__ out) {
    int tid = threadIdx.x;
    int j = blockIdx.x * 16 + (tid >> 4);        // 16 rows/block, 16 threads/row
    int c0 = (tid & 15) * 16;                    // 16 channels/thread
    int b = j >> 13;
    const u16* fb = f2t + (size_t)b * 2048 * 256;
    const u16* r0 = fb + (size_t)idx[j * 3 + 0] * 256 + c0;
    const u16* r1 = fb + (size_t)idx[j * 3 + 1] * 256 + c0;
    const u16* r2 = fb + (size_t)idx[j * 3 + 2] * 256 + c0;
    float w0 = wgt[j * 3 + 0], w1 = wgt[j * 3 + 1], w2 = wgt[j * 3 + 2];
    u16* ob = out + (size_t)j * 256 + c0;
#pragma unroll
    for (int cc = 0; cc < 2; ++cc) {
        u16x8 v0 = *(const u16x8*)(r0 + cc * 8);
        u16x8 v1 = *(const u16x8*)(r1 + cc * 8);
        u16x8 v2 = *(const u16x8*)(r2 + cc * 8);
        u16x8 o;
#pragma unroll
        for (int e = 0; e < 8; ++e)
            o[e] = f2b(w0 * b2f(v0[e]) + w1 * b2f(v1[e]) + w2 * b2f(v2[e]));
        *(u16x8*)(ob + cc * 8) = o;
    }
}

// ---------- shared BN-reduce slice: P[512][512] rows -> folded (scale, shift) ----------
__device__ __forceinline__ void reduce_slice(const float* __restrict__ P,
                                             const float* __restrict__ g,
                                             const float* __restrict__ be,
                                             float2* __restrict__ bnt,
                                             int slice, int tid,
                                             float* ls, float* ls2) {
    int l = tid & 63, rg = tid >> 6;
    int ch = slice * 64 + l;
    float s = 0.f, s2 = 0.f;
    for (int r = rg * 128; r < rg * 128 + 128; ++r) {
        s += P[(size_t)r * 512 + ch];
        s2 += P[(size_t)r * 512 + 256 + ch];
    }
    ls[rg * 64 + l] = s; ls2[rg * 64 + l] = s2;
    __syncthreads();
    if (tid < 64) {
        float fs = ls[tid] + ls[64 + tid] + ls[128 + tid] + ls[192 + tid];
        float fs2 = ls2[tid] + ls2[64 + tid] + ls2[128 + tid] + ls2[192 + tid];
        int c = slice * 64 + tid;
        const float inv = 1.f / 32768.f;
        float mean = fs * inv;
        float var = fs2 * inv - mean * mean;
        float a = g[c] * rsqrtf(var + 1e-5f);
        bnt[c] = make_float2(a, be[c] - mean * a);
    }
}

// ---------- GEMM1: Yb[j][m] = bf16(sum_k A[j][k]*Bw[m][k] + bias[m]) ----------
// Dense A: k<256 from A1 (INTERP, stride 256), k>=256 from A2 (F1T, stride 128).
// Writes per-channel BN partials to P (each slot once). Also zeroes BAR for gemm2_fused.
__global__ __launch_bounds__(256, 2) void gemm1_kernel(const u16* __restrict__ A1,
                                                       const u16* __restrict__ A2,
                                                       const u16* __restrict__ Bw,
                                                       const float* __restrict__ bias,
                                                       u16* __restrict__ Yb,
                                                       float* __restrict__ Pt,
                                                       int* __restrict__ BAR) {
    __shared__ __align__(16) char smemA[36864];
    u16* Al = (u16*)smemA;                       // [128][64], k-loop (swizzled cols)
    u16* Bl = (u16*)(smemA + 16384);             // [128][64], k-loop (swizzled cols)
    u16* T  = (u16*)smemA;                       // [128][136] epilogue bounce (overlays Al/Bl)
    int tid = threadIdx.x;
    if (blockIdx.x == 0 && blockIdx.y == 0 && tid == 0) *BAR = 0;   // arm grid barrier
    int lane = tid & 63, wv = tid >> 6;
    int j0 = blockIdx.x * 128, m0 = blockIdx.y * 128;
    int l15 = lane & 15, q = lane >> 4;
    int wj = (wv >> 1) * 64, wm = (wv & 1) * 64;
    f32x4 acc[4][4];
#pragma unroll
    for (int i = 0; i < 4; ++i)
#pragma unroll
        for (int jj = 0; jj < 4; ++jj) acc[i][jj] = (f32x4){0.f, 0.f, 0.f, 0.f};

    int rbase = wv * 32;
    int lrow = lane >> 3, lchunk = lane & 7;
    int schunk = lchunk ^ lrow;                  // swizzled chunk for staging
    const u16* Bg = Bw + (size_t)m0 * 384;

    for (int k0 = 0; k0 < 384; k0 += 64) {
#pragma unroll
        for (int qq = 0; qq < 4; ++qq) {
            int row = rbase + qq * 8;
            async_cp16(&Bl[row * 64], Bg + (size_t)(row + lrow) * 384 + k0 + schunk * 8);
        }
        const u16* src; int str;
        if (k0 < 256) { src = A1 + (size_t)j0 * 256 + k0;         str = 256; }
        else          { src = A2 + (size_t)j0 * 128 + (k0 - 256); str = 128; }
#pragma unroll
        for (int qq = 0; qq < 4; ++qq) {
            int row = rbase + qq * 8;
            async_cp16(&Al[row * 64], src + (size_t)(row + lrow) * str + schunk * 8);
        }
        __syncthreads();
#pragma unroll
        for (int ks = 0; ks < 2; ++ks) {
            bf16x8 af[4], bfr[4];
#pragma unroll
            for (int i = 0; i < 4; ++i) {
                int row = wj + i * 16 + l15;
                af[i] = *(const bf16x8*)&Al[row * 64 + ((ks * 4 + q) ^ (l15 & 7)) * 8];
            }
#pragma unroll
            for (int i = 0; i < 4; ++i) {
                int row = wm + i * 16 + l15;
                bfr[i] = *(const bf16x8*)&Bl[row * 64 + ((ks * 4 + q) ^ (l15 & 7)) * 8];
            }
#pragma unroll
            for (int i = 0; i < 4; ++i)
#pragma unroll
                for (int jj = 0; jj < 4; ++jj)
                    acc[i][jj] = __builtin_amdgcn_mfma_f32_16x16x32_bf16(af[i], bfr[jj],
                                                                         acc[i][jj], 0, 0, 0);
        }
        __syncthreads();
    }
    // epilogue: per-channel partials + bf16 tile into LDS
#pragma unroll
    for (int jj = 0; jj < 4; ++jj) {
        int ml = wm + jj * 16 + l15;
        float bv = bias[m0 + ml];
        float s = 0.f, s2 = 0.f;
#pragma unroll
        for (int i = 0; i < 4; ++i) {
            int jl = wj + i * 16 + q * 4;
#pragma unroll
            for (int r = 0; r < 4; ++r) {
                float v = acc[i][jj][r] + bv;
                s += v; s2 += v * v;
                T[(jl + r) * 136 + ml] = f2b(v);
            }
        }
        s += __shfl_xor(s, 16); s += __shfl_xor(s, 32);
        s2 += __shfl_xor(s2, 16); s2 += __shfl_xor(s2, 32);
        if (q == 0) {
            size_t prow = (size_t)blockIdx.x * 2 + (wv >> 1);
            Pt[prow * 512 + (m0 + ml)] = s;
            Pt[prow * 512 + 256 + (m0 + ml)] = s2;
        }
    }
    __syncthreads();
#pragma unroll
    for (int it = 0; it < 8; ++it) {
        int jl = it * 16 + wv * 4 + q;
        u16x8 v = *(const u16x8*)&T[jl * 136 + l15 * 8];
        *(u16x8*)&Yb[(size_t)(j0 + jl) * 256 + m0 + l15 * 8] = v;
    }
}

// ---------- gemm2_fused: reduce1 -> BN1+ReLU-fused GEMM2 -> reduce2 -> BN2+transpose ----------
// Manual grid barrier: grid=512, __launch_bounds__(256,2) guarantees >=2 blocks/CU
// co-resident (LDS 36.9KB allows 4) so all 512 blocks are resident -> spin is safe.
// BAR[0] zeroed by gemm1 earlier in the stream (fresh each graph replay).
__device__ __forceinline__ void gridbar(int* cnt, int target) {
    __threadfence();                 // release: prior stores visible device-wide (wbl2)
    __syncthreads();
    if (threadIdx.x == 0) {
        __hip_atomic_fetch_add(cnt, 1, __ATOMIC_RELEASE, __HIP_MEMORY_SCOPE_AGENT);
        while (__hip_atomic_load(cnt, __ATOMIC_ACQUIRE, __HIP_MEMORY_SCOPE_AGENT) < target)
            __builtin_amdgcn_s_sleep(2);
    }
    __syncthreads();
    __threadfence();                 // acquire for all threads of the block
}

__global__ __launch_bounds__(256, 2) void gemm2_fused(const u16* __restrict__ Y1,
                                                      const u16* __restrict__ Bw,
                                                      const float* __restrict__ bias,
                                                      const float* __restrict__ P1,
                                                      const float* __restrict__ g1,
                                                      const float* __restrict__ be1,
                                                      float2* __restrict__ BNT1G,
                                                      float* __restrict__ P2,
                                                      const float* __restrict__ g2,
                                                      const float* __restrict__ be2,
                                                      float2* __restrict__ BNT2G,
                                                      float* __restrict__ OUT,
                                                      int* __restrict__ BAR) {
    __shared__ __align__(16) char smemA[36864];
    u16* Al = (u16*)smemA;                       // [128][64]
    u16* Bl = (u16*)(smemA + 16384);             // [128][64]
    u16* T  = (u16*)smemA;                       // [128][136] bf16, TRANSPOSED: [m][j]
    float2* BNT = (float2*)(smemA + 34816);      // 256 x (scale, shift) / reduce scratch
    float* ls  = (float*)(smemA + 34816);
    float* ls2 = (float*)(smemA + 34816 + 1024);
    int tid = threadIdx.x;
    int bid = blockIdx.x;
    int lane = tid & 63, wv = tid >> 6;
    int j0 = (bid >> 1) * 128, m0 = (bid & 1) * 128;
    int l15 = lane & 15, q = lane >> 4;
    int wj = (wv >> 1) * 64, wm = (wv & 1) * 64;

    // ---- phase 0: blocks 0..3 fold BN1 from P1 ----
    if (bid < 4) reduce_slice(P1, g1, be1, BNT1G, bid, tid, ls, ls2);
    gridbar(BAR, 512);

    // ---- phase 1: BN1-fused GEMM (KT=256, A=relu(bn1(Y1))) ----
    BNT[tid] = BNT1G[tid];
    __syncthreads();

    f32x4 acc[4][4];
#pragma unroll
    for (int i = 0; i < 4; ++i)
#pragma unroll
        for (int jj = 0; jj < 4; ++jj) acc[i][jj] = (f32x4){0.f, 0.f, 0.f, 0.f};

    int rbase = wv * 32;
    int lrow = lane >> 3, lchunk = lane & 7;
    int schunk = lchunk ^ lrow;
    const u16* Bg = Bw + (size_t)m0 * 256;

    for (int k0 = 0; k0 < 256; k0 += 64) {
#pragma unroll
        for (int qq = 0; qq < 4; ++qq) {
            int row = rbase + qq * 8;
            async_cp16(&Bl[row * 64], Bg + (size_t)(row + lrow) * 256 + k0 + schunk * 8);
        }
        int c = k0 + lchunk * 8;
        float2 bn[8];
#pragma unroll
        for (int e = 0; e < 8; ++e) bn[e] = BNT[c + e];
#pragma unroll
        for (int qq = 0; qq < 4; ++qq) {
            int row = rbase + qq * 8;
            u16x8 y = *(const u16x8*)&Y1[(size_t)(j0 + row + lrow) * 256 + c];
            u16x8 o;
#pragma unroll
            for (int e = 0; e < 8; ++e)
                o[e] = f2b(fmaxf(b2f(y[e]) * bn[e].x + bn[e].y, 0.f));
            *(u16x8*)&Al[(row + lrow) * 64 + schunk * 8] = o;
        }
        __syncthreads();
#pragma unroll
        for (int ks = 0; ks < 2; ++ks) {
            bf16x8 af[4], bfr[4];
#pragma unroll
            for (int i = 0; i < 4; ++i) {
                int row = wj + i * 16 + l15;
                af[i] = *(const bf16x8*)&Al[row * 64 + ((ks * 4 + q) ^ (l15 & 7)) * 8];
            }
#pragma unroll
            for (int i = 0; i < 4; ++i) {
                int row = wm + i * 16 + l15;
                bfr[i] = *(const bf16x8*)&Bl[row * 64 + ((ks * 4 + q) ^ (l15 & 7)) * 8];
            }
#pragma unroll
            for (int i = 0; i < 4; ++i)
#pragma unroll
                for (int jj = 0; jj < 4; ++jj)
                    acc[i][jj] = __builtin_amdgcn_mfma_f32_16x16x32_bf16(af[i], bfr[jj],
                                                                         acc[i][jj], 0, 0, 0);
        }
        __syncthreads();
    }

    // ---- phase 2: partials + bf16 tile into LDS TRANSPOSED [m][j] ----
#pragma unroll
    for (int jj = 0; jj < 4; ++jj) {
        int ml = wm + jj * 16 + l15;
        float bv = bias[m0 + ml];
        float s = 0.f, s2 = 0.f;
#pragma unroll
        for (int i = 0; i < 4; ++i) {
            int jl = wj + i * 16 + q * 4;
#pragma unroll
            for (int r = 0; r < 4; ++r) {
                float v = acc[i][jj][r] + bv;
                s += v; s2 += v * v;
                T[ml * 136 + (jl + r)] = f2b(v);   // [m][j] for transposed store
            }
        }
        s += __shfl_xor(s, 16); s += __shfl_xor(s, 32);
        s2 += __shfl_xor(s2, 16); s2 += __shfl_xor(s2, 32);
        if (q == 0) {
            size_t prow = (size_t)(bid >> 1) * 2 + (wv >> 1);
            P2[prow * 512 + (m0 + ml)] = s;
            P2[prow * 512 + 256 + (m0 + ml)] = s2;
        }
    }
    gridbar(BAR, 1024);

    // ---- phase 3: blocks 0..3 fold BN2 from P2 (ls region free; T untouched) ----
    if (bid < 4) reduce_slice(P2, g2, be2, BNT2G, bid, tid, ls, ls2);
    gridbar(BAR, 1536);

    // ---- phase 4: BN2+ReLU from T, transposed store out[b][o][n] ----
    float2* BNTo = (float2*)(smemA + 34816);
    if (tid < 128) BNTo[tid] = BNT2G[m0 + tid];
    __syncthreads();
    int ol8 = tid >> 5;              // 0..7
    int j4 = (tid & 31) * 4;         // 0..124
    int bb = j0 >> 13, n0 = j0 & 8191;
#pragma unroll
    for (int it = 0; it < 16; ++it) {
        int ol = it * 8 + ol8;
        float2 bn = BNTo[ol];
        ushort4 h = *(const ushort4*)&T[ol * 136 + j4];
        float4 v;
        v.x = fmaxf(b2f(h.x) * bn.x + bn.y, 0.f);
        v.y = fmaxf(b2f(h.y) * bn.x + bn.y, 0.f);
        v.z = fmaxf(b2f(h.z) * bn.x + bn.y, 0.f);
        v.w = fmaxf(b2f(h.w) * bn.x + bn.y, 0.f);
        *(float4*)&OUT[(size_t)bb * 2097152 + (size_t)(m0 + ol) * 8192 + n0 + j4] = v;
    }
}

extern "C" void kernel_launch(void* const* d_in, const int* in_sizes, int n_in,
                              void* d_out, int out_size, void* d_ws, size_t ws_size,
                              hipStream_t stream) {
    const float* pos1 = (const float*)d_in[0];
    const float* pos2 = (const float*)d_in[1];
    const float* feature1 = (const float*)d_in[2];
    const float* feature2 = (const float*)d_in[3];
    const float* W1 = (const float*)d_in[4];
    const float* b1 = (const float*)d_in[5];
    const float* g1 = (const float*)d_in[6];
    const float* be1 = (const float*)d_in[7];
    const float* W2 = (const float*)d_in[8];
    const float* b2 = (const float*)d_in[9];
    const float* g2 = (const float*)d_in[10];
    const float* be2 = (const float*)d_in[11];

    char* ws = (char*)d_ws;
    int*    IDX   = (int*)(ws + 0);                 // 393216 B
    float*  WGT   = (float*)(ws + 393216);          // 393216 B
    u16*    W1B   = (u16*)(ws + 786432);            // 196608 B
    u16*    W2B   = (u16*)(ws + 983040);            // 131072 B (contiguous after W1B)
    float2* BNT1G = (float2*)(ws + 1114112);        // 2048 B folded BN1 (scale, shift)
    float2* BNT2G = (float2*)(ws + 1116160);        // 2048 B folded BN2
    u16*    F2T   = (u16*)(ws + 1118208);           // 4 MiB  [4][2048][256]
    u16*    F1T   = (u16*)(ws + 5312512);           // 8 MiB  [4][8192][128]
    u16*    Y1    = (u16*)(ws + 13701120);          // 16 MiB [32768][256]
    u16*    INTERP= (u16*)(ws + 30478336);          // 16 MiB [32768][256] bf16
    float*  P1    = (float*)(ws + 47255552);        // 1 MiB [512][512] partials gemm1
    float*  P2    = (float*)(ws + 48304128);        // 1 MiB partials gemm2
    int*    BAR   = (int*)(ws + 49352704);          // grid-barrier counter
    float*  OUT   = (float*)d_out;

    prep_kernel<<<NB_NN + NB_CVT + NB_T2 + NB_T1, 256, 0, stream>>>(
        W1, W2, W1B, feature2, F2T, feature1, F1T, pos1, pos2, IDX, WGT);
    interp_kernel<<<2048, 256, 0, stream>>>(F2T, IDX, WGT, INTERP);
    gemm1_kernel<<<dim3(256, 2), 256, 0, stream>>>(INTERP, F1T, W1B, b1, Y1, P1, BAR);
    gemm2_fused<<<512, 256, 0, stream>>>(Y1, W2B, b2, P1, g1, be1, BNT1G,
                                         P2, g2, be2, BNT2G, OUT, BAR);
}

// Round 3
// 259.394 us; speedup vs baseline: 3.1095x; 3.1095x over previous
//
#include <hip/hip_runtime.h>
#include <hip/hip_bf16.h>
#include <cstdint>

typedef unsigned short u16;
typedef unsigned int u32;
typedef unsigned long long u64;
typedef __bf16 bf16x8 __attribute__((ext_vector_type(8)));
typedef float f32x4 __attribute__((ext_vector_type(4)));
typedef u16 u16x8 __attribute__((ext_vector_type(8)));

// ---------- helpers ----------
__device__ __forceinline__ u16 f2b(float f) {          // fp32 -> bf16 RNE
    unsigned int u = __float_as_uint(f);
    u += 0x7fffu + ((u >> 16) & 1u);
    return (u16)(u >> 16);
}
__device__ __forceinline__ float b2f(u16 h) {
    return __uint_as_float(((unsigned int)h) << 16);
}
__device__ __forceinline__ void async_cp16(void* lds, const void* g) {
    __builtin_amdgcn_global_load_lds((const __attribute__((address_space(1))) void*)g,
                                     (__attribute__((address_space(3))) void*)lds, 16, 0, 0);
}
// agent-scope coherent accessors (write-through / LLC-read; NO cache-maintenance ops)
__device__ __forceinline__ void st_agent_f32(float* p, float v) {
    __hip_atomic_store(p, v, __ATOMIC_RELAXED, __HIP_MEMORY_SCOPE_AGENT);
}
__device__ __forceinline__ float ld_agent_f32(const float* p) {
    return __hip_atomic_load(p, __ATOMIC_RELAXED, __HIP_MEMORY_SCOPE_AGENT);
}
__device__ __forceinline__ void st_agent_f2(float2* p, float2 v) {
    union { float2 f; u64 u; } cv; cv.f = v;
    __hip_atomic_store((u64*)p, cv.u, __ATOMIC_RELAXED, __HIP_MEMORY_SCOPE_AGENT);
}
__device__ __forceinline__ float2 ld_agent_f2(const float2* p) {
    union { u64 u; float2 f; } cv;
    cv.u = __hip_atomic_load((const u64*)p, __ATOMIC_RELAXED, __HIP_MEMORY_SCOPE_AGENT);
    return cv.f;
}
// monotone unsigned mapping of float bits (order-preserving, EXACT)
__device__ __forceinline__ u32 fmono(float f) {
    u32 u = __float_as_uint(f);
    return u ^ (((u32)((int)u >> 31)) | 0x80000000u);
}
__device__ __forceinline__ u64 shfl_xor_u64(u64 v, int mask) {
    u32 lo = (u32)v, hi = (u32)(v >> 32);
    lo = (u32)__shfl_xor((int)lo, mask);
    hi = (u32)__shfl_xor((int)hi, mask);
    return ((u64)hi << 32) | lo;
}
// insert exact key into descending top-3 (keys unique: idx field breaks ties)
__device__ __forceinline__ void ins3(u64 k, u64& k0, u64& k1, u64& k2) {
    bool c0 = k > k0, c1 = k > k1, c2 = k > k2;
    k2 = c1 ? k1 : (c2 ? k : k2);
    k1 = c0 ? k0 : (c1 ? k : k1);
    k0 = c0 ? k : k0;
}
// padded pk index: one float4 pad every 64 entries (chunk groups on distinct banks)
__device__ __forceinline__ int pkix(int i) { return i + (i >> 6); }

// ================= prep kernel: three_nn FIRST, then cvt + transposes =================
#define NB_NN  1024
#define NB_CVT 160
#define NB_T2  512
#define NB_T1  1024

__global__ __launch_bounds__(256, 6) void prep_kernel(const float* __restrict__ w1,
                                                      const float* __restrict__ w2,
                                                      u16* __restrict__ wb,
                                                      const float* __restrict__ feature2,
                                                      u16* __restrict__ f2t,
                                                      const float* __restrict__ feature1,
                                                      u16* __restrict__ f1t,
                                                      const float* __restrict__ pos1,
                                                      const float* __restrict__ pos2,
                                                      int* __restrict__ idx_out,
                                                      float* __restrict__ w_out) {
    __shared__ __align__(16) char smem[19712];   // 16640 pk-half + 3072 warr
    int bi = blockIdx.x;
    int tid = threadIdx.x;

    if (bi >= NB_NN) {
        int ci = bi - NB_NN;
        if (ci < NB_CVT) {
            int i = ci * 256 + tid;
            if (i < 40960) {
                const float* src = (i < 24576) ? w1 : w2;
                int k = (i < 24576) ? i : (i - 24576);
                float4 v = *(const float4*)&src[(size_t)k * 4];
                ushort4 o;
                o.x = f2b(v.x); o.y = f2b(v.y); o.z = f2b(v.z); o.w = f2b(v.w);
                *(ushort4*)&wb[(size_t)i * 4] = o;
            }
            return;
        }
        // ---- transpose [B][C][S] -> [B][S][C] bf16 ----
        float (*t)[65] = (float (*)[65])smem;
        const float* in; u16* out; int C, S, s0, c0, b;
        if (ci < NB_CVT + NB_T2) {
            int lin = ci - NB_CVT;
            C = 256; S = 2048; in = feature2; out = f2t;
            s0 = (lin & 31) * 64; c0 = ((lin >> 5) & 3) * 64; b = lin >> 7;
        } else {
            int lin = ci - NB_CVT - NB_T2;
            C = 128; S = 8192; in = feature1; out = f1t;
            s0 = (lin & 127) * 64; c0 = ((lin >> 7) & 1) * 64; b = lin >> 8;
        }
        const float* ib = in + (size_t)b * C * S;
        u16* ob = out + (size_t)b * S * C;
        int col = tid & 63, r0 = tid >> 6;
#pragma unroll
        for (int p = 0; p < 16; ++p) {
            int c = p * 4 + r0;
            t[c][col] = ib[(size_t)(c0 + c) * S + s0 + col];
        }
        __syncthreads();
#pragma unroll
        for (int p = 0; p < 16; ++p) {
            int s = p * 4 + r0;
            ob[(size_t)(s0 + s) * C + c0 + col] = f2b(t[col][s]);
        }
        return;
    }

    // ---- three_nn: 32 queries/block; thread handles queries p, p+16 ----
    float4* pk = (float4*)smem;                          // padded: 1040 float4 = 16640 B
    u64* warr = (u64*)(smem + 16640);                    // [4 waves][16 p][2 t][3]
    int j0 = bi * 32;
    int b = j0 >> 13;
    const float* p2 = pos2 + (size_t)b * 3 * 2048;
    int p = tid & 15, ck = tid >> 4;
    int wv = tid >> 6, lane = tid & 63;
    const float* p1 = pos1 + (size_t)b * 3 * 8192;
    float qx[2], qy[2], qz[2];
#pragma unroll
    for (int t = 0; t < 2; ++t) {
        int n = (j0 & 8191) + p + t * 16;
        qx[t] = p1[n]; qy[t] = p1[8192 + n]; qz[t] = p1[16384 + n];
    }
    u64 key[2][3];
#pragma unroll
    for (int t = 0; t < 2; ++t) { key[t][0] = 0; key[t][1] = 0; key[t][2] = 0; }

    for (int half = 0; half < 2; ++half) {
        int hbase = half * 1024;
        for (int i = tid; i < 1024; i += 256) {
            int s = hbase + i;
            float x = p2[s], y = p2[2048 + s], z = p2[4096 + s];
            pk[pkix(i)] = make_float4(x, y, z, -0.5f * (x * x + y * y + z * z));
        }
        __syncthreads();

        float g[2][3]; int id[2][3];
#pragma unroll
        for (int t = 0; t < 2; ++t) {
            g[t][0] = -3.4e38f; g[t][1] = -3.4e38f; g[t][2] = -3.4e38f;
            id[t][0] = 0; id[t][1] = 0; id[t][2] = 0;
        }
        int sb = ck * 64;
        const float4* pc = pk + pkix(sb);
#pragma unroll 2
        for (int it = 0; it < 64; ++it) {
            float4 cd = pc[it];
            int s = sb + it;
#pragma unroll
            for (int t = 0; t < 2; ++t) {
                float tv = fmaf(qx[t], cd.x, fmaf(qy[t], cd.y, fmaf(qz[t], cd.z, cd.w)));
                bool c0 = tv > g[t][0], c1 = tv > g[t][1], c2 = tv > g[t][2];
                float o0 = g[t][0], o1 = g[t][1];
                g[t][2] = __builtin_amdgcn_fmed3f(tv, o1, g[t][2]);
                g[t][1] = __builtin_amdgcn_fmed3f(tv, o0, o1);
                g[t][0] = fmaxf(o0, tv);
                id[t][2] = c1 ? id[t][1] : (c2 ? s : id[t][2]);
                id[t][1] = c0 ? id[t][0] : (c1 ? s : id[t][1]);
                id[t][0] = c0 ? s : id[t][0];
            }
        }
        __syncthreads();   // reads done before next half restages

#pragma unroll
        for (int t = 0; t < 2; ++t) {
#pragma unroll
            for (int r = 0; r < 3; ++r)
                ins3(((u64)fmono(g[t][r]) << 32) | (u64)(2047 - (hbase + id[t][r])),
                     key[t][0], key[t][1], key[t][2]);
        }
    }

    // in-wave merge across the 4 chunk-groups (lane>>4)
#pragma unroll
    for (int mask = 16; mask <= 32; mask <<= 1) {
#pragma unroll
        for (int t = 0; t < 2; ++t) {
            u64 m0 = shfl_xor_u64(key[t][0], mask);
            u64 m1 = shfl_xor_u64(key[t][1], mask);
            u64 m2 = shfl_xor_u64(key[t][2], mask);
            ins3(m0, key[t][0], key[t][1], key[t][2]);
            ins3(m1, key[t][0], key[t][1], key[t][2]);
            ins3(m2, key[t][0], key[t][1], key[t][2]);
        }
    }
    if (lane < 16) {
        u64* wr = &warr[(wv * 16 + p) * 6];
#pragma unroll
        for (int t = 0; t < 2; ++t) {
            wr[t * 3 + 0] = key[t][0]; wr[t * 3 + 1] = key[t][1]; wr[t * 3 + 2] = key[t][2];
        }
    }
    __syncthreads();
    if (tid < 32) {
        int pp = tid & 15, t = tid >> 4;
        const u64* w0 = &warr[pp * 6 + t * 3];
        u64 k0 = w0[0], k1 = w0[1], k2 = w0[2];
#pragma unroll
        for (int w = 1; w < 4; ++w) {
            const u64* wr = &warr[(w * 16 + pp) * 6 + t * 3];
            ins3(wr[0], k0, k1, k2);
            ins3(wr[1], k0, k1, k2);
            ins3(wr[2], k0, k1, k2);
        }
        int s0 = 2047 - (int)(k0 & 0xFFFFFFFFu);
        int s1 = 2047 - (int)(k1 & 0xFFFFFFFFu);
        int s2 = 2047 - (int)(k2 & 0xFFFFFFFFu);
        int j = j0 + pp + t * 16;
        int n = j & 8191;
        float x1 = p1[n], y1 = p1[8192 + n], z1 = p1[16384 + n];
        float n1 = x1 * x1 + y1 * y1 + z1 * z1;
        float X0 = p2[s0], Y0 = p2[2048 + s0], Z0 = p2[4096 + s0];
        float X1 = p2[s1], Y1v = p2[2048 + s1], Z1 = p2[4096 + s1];
        float X2 = p2[s2], Y2v = p2[2048 + s2], Z2 = p2[4096 + s2];
        float t0 = x1 * X0 + y1 * Y0 + z1 * Z0 - 0.5f * (X0 * X0 + Y0 * Y0 + Z0 * Z0);
        float t1 = x1 * X1 + y1 * Y1v + z1 * Z1 - 0.5f * (X1 * X1 + Y1v * Y1v + Z1 * Z1);
        float t2 = x1 * X2 + y1 * Y2v + z1 * Z2 - 0.5f * (X2 * X2 + Y2v * Y2v + Z2 * Z2);
        float d0 = fmaxf(fmaf(-2.f, t0, n1), 1e-10f);
        float d1 = fmaxf(fmaf(-2.f, t1, n1), 1e-10f);
        float d2 = fmaxf(fmaf(-2.f, t2, n1), 1e-10f);
        float w0v = 1.f / d0, w1v = 1.f / d1, w2v = 1.f / d2;
        float inv = 1.f / (w0v + w1v + w2v);
        idx_out[j * 3] = s0; idx_out[j * 3 + 1] = s1; idx_out[j * 3 + 2] = s2;
        w_out[j * 3] = w0v * inv; w_out[j * 3 + 1] = w1v * inv; w_out[j * 3 + 2] = w2v * inv;
    }
}

// ---------- interp: gather 3 rows of F2T, weighted sum -> bf16 [32768][256] ----------
__global__ __launch_bounds__(256, 8) void interp_kernel(const u16* __restrict__ f2t,
                                                        const int* __restrict__ idx,
                                                        const float* __restrict__ wgt,
                                                        u16* __restrict__ out) {
    int tid = threadIdx.x;
    int j = blockIdx.x * 16 + (tid >> 4);        // 16 rows/block, 16 threads/row
    int c0 = (tid & 15) * 16;                    // 16 channels/thread
    int b = j >> 13;
    const u16* fb = f2t + (size_t)b * 2048 * 256;
    const u16* r0 = fb + (size_t)idx[j * 3 + 0] * 256 + c0;
    const u16* r1 = fb + (size_t)idx[j * 3 + 1] * 256 + c0;
    const u16* r2 = fb + (size_t)idx[j * 3 + 2] * 256 + c0;
    float w0 = wgt[j * 3 + 0], w1 = wgt[j * 3 + 1], w2 = wgt[j * 3 + 2];
    u16* ob = out + (size_t)j * 256 + c0;
#pragma unroll
    for (int cc = 0; cc < 2; ++cc) {
        u16x8 v0 = *(const u16x8*)(r0 + cc * 8);
        u16x8 v1 = *(const u16x8*)(r1 + cc * 8);
        u16x8 v2 = *(const u16x8*)(r2 + cc * 8);
        u16x8 o;
#pragma unroll
        for (int e = 0; e < 8; ++e)
            o[e] = f2b(w0 * b2f(v0[e]) + w1 * b2f(v1[e]) + w2 * b2f(v2[e]));
        *(u16x8*)(ob + cc * 8) = o;
    }
}

// ---------- shared BN-reduce slice: P[512][512] rows -> folded (scale, shift) ----------
// P read via agent-scope loads (coherent at LLC); bnt written via agent-scope stores.
__device__ __forceinline__ void reduce_slice(const float* __restrict__ P,
                                             const float* __restrict__ g,
                                             const float* __restrict__ be,
                                             float2* __restrict__ bnt,
                                             int slice, int tid,
                                             float* ls, float* ls2) {
    int l = tid & 63, rg = tid >> 6;
    int ch = slice * 64 + l;
    float s = 0.f, s2 = 0.f;
    for (int r = rg * 128; r < rg * 128 + 128; ++r) {
        s += ld_agent_f32(&P[(size_t)r * 512 + ch]);
        s2 += ld_agent_f32(&P[(size_t)r * 512 + 256 + ch]);
    }
    ls[rg * 64 + l] = s; ls2[rg * 64 + l] = s2;
    __syncthreads();
    if (tid < 64) {
        float fs = ls[tid] + ls[64 + tid] + ls[128 + tid] + ls[192 + tid];
        float fs2 = ls2[tid] + ls2[64 + tid] + ls2[128 + tid] + ls2[192 + tid];
        int c = slice * 64 + tid;
        const float inv = 1.f / 32768.f;
        float mean = fs * inv;
        float var = fs2 * inv - mean * mean;
        float a = g[c] * rsqrtf(var + 1e-5f);
        st_agent_f2(&bnt[c], make_float2(a, be[c] - mean * a));
    }
}

// ---------- GEMM1: Yb[j][m] = bf16(sum_k A[j][k]*Bw[m][k] + bias[m]) ----------
__global__ __launch_bounds__(256, 2) void gemm1_kernel(const u16* __restrict__ A1,
                                                       const u16* __restrict__ A2,
                                                       const u16* __restrict__ Bw,
                                                       const float* __restrict__ bias,
                                                       u16* __restrict__ Yb,
                                                       float* __restrict__ Pt,
                                                       int* __restrict__ BAR) {
    __shared__ __align__(16) char smemA[36864];
    u16* Al = (u16*)smemA;                       // [128][64], k-loop (swizzled cols)
    u16* Bl = (u16*)(smemA + 16384);             // [128][64], k-loop (swizzled cols)
    u16* T  = (u16*)smemA;                       // [128][136] epilogue bounce (overlays Al/Bl)
    int tid = threadIdx.x;
    if (blockIdx.x == 0 && blockIdx.y == 0 && tid == 0) *BAR = 0;   // arm grid barrier
    int lane = tid & 63, wv = tid >> 6;
    int j0 = blockIdx.x * 128, m0 = blockIdx.y * 128;
    int l15 = lane & 15, q = lane >> 4;
    int wj = (wv >> 1) * 64, wm = (wv & 1) * 64;
    f32x4 acc[4][4];
#pragma unroll
    for (int i = 0; i < 4; ++i)
#pragma unroll
        for (int jj = 0; jj < 4; ++jj) acc[i][jj] = (f32x4){0.f, 0.f, 0.f, 0.f};

    int rbase = wv * 32;
    int lrow = lane >> 3, lchunk = lane & 7;
    int schunk = lchunk ^ lrow;                  // swizzled chunk for staging
    const u16* Bg = Bw + (size_t)m0 * 384;

    for (int k0 = 0; k0 < 384; k0 += 64) {
#pragma unroll
        for (int qq = 0; qq < 4; ++qq) {
            int row = rbase + qq * 8;
            async_cp16(&Bl[row * 64], Bg + (size_t)(row + lrow) * 384 + k0 + schunk * 8);
        }
        const u16* src; int str;
        if (k0 < 256) { src = A1 + (size_t)j0 * 256 + k0;         str = 256; }
        else          { src = A2 + (size_t)j0 * 128 + (k0 - 256); str = 128; }
#pragma unroll
        for (int qq = 0; qq < 4; ++qq) {
            int row = rbase + qq * 8;
            async_cp16(&Al[row * 64], src + (size_t)(row + lrow) * str + schunk * 8);
        }
        __syncthreads();
#pragma unroll
        for (int ks = 0; ks < 2; ++ks) {
            bf16x8 af[4], bfr[4];
#pragma unroll
            for (int i = 0; i < 4; ++i) {
                int row = wj + i * 16 + l15;
                af[i] = *(const bf16x8*)&Al[row * 64 + ((ks * 4 + q) ^ (l15 & 7)) * 8];
            }
#pragma unroll
            for (int i = 0; i < 4; ++i) {
                int row = wm + i * 16 + l15;
                bfr[i] = *(const bf16x8*)&Bl[row * 64 + ((ks * 4 + q) ^ (l15 & 7)) * 8];
            }
#pragma unroll
            for (int i = 0; i < 4; ++i)
#pragma unroll
                for (int jj = 0; jj < 4; ++jj)
                    acc[i][jj] = __builtin_amdgcn_mfma_f32_16x16x32_bf16(af[i], bfr[jj],
                                                                         acc[i][jj], 0, 0, 0);
        }
        __syncthreads();
    }
    // epilogue: per-channel partials + bf16 tile into LDS
#pragma unroll
    for (int jj = 0; jj < 4; ++jj) {
        int ml = wm + jj * 16 + l15;
        float bv = bias[m0 + ml];
        float s = 0.f, s2 = 0.f;
#pragma unroll
        for (int i = 0; i < 4; ++i) {
            int jl = wj + i * 16 + q * 4;
#pragma unroll
            for (int r = 0; r < 4; ++r) {
                float v = acc[i][jj][r] + bv;
                s += v; s2 += v * v;
                T[(jl + r) * 136 + ml] = f2b(v);
            }
        }
        s += __shfl_xor(s, 16); s += __shfl_xor(s, 32);
        s2 += __shfl_xor(s2, 16); s2 += __shfl_xor(s2, 32);
        if (q == 0) {
            size_t prow = (size_t)blockIdx.x * 2 + (wv >> 1);
            Pt[prow * 512 + (m0 + ml)] = s;            // plain: consumed by NEXT kernel
            Pt[prow * 512 + 256 + (m0 + ml)] = s2;
        }
    }
    __syncthreads();
#pragma unroll
    for (int it = 0; it < 8; ++it) {
        int jl = it * 16 + wv * 4 + q;
        u16x8 v = *(const u16x8*)&T[jl * 136 + l15 * 8];
        *(u16x8*)&Yb[(size_t)(j0 + jl) * 256 + m0 + l15 * 8] = v;
    }
}

// ---------- gemm2_fused: reduce1 -> BN1-fused GEMM2 -> reduce2 -> BN2+transpose ----------
// Grid barrier with ZERO cache-maintenance ops: cross-barrier data (BNT1G/P2/BNT2G) is
// written/read with agent-scope relaxed atomics (write-through at LLC / LLC-read), so no
// wbl2/inv is needed. Arrive = relaxed fetch_add(1); poll = relaxed fetch_add(0)
// (RMW -> always coherent, cannot spin on a stale cache line); s_sleep between polls.
// Round-2 post-mortem: per-thread __threadfence + per-poll ACQUIRE load = L2
// writeback/invalidate storm -> 660us idle. This design has no maintenance ops at all.
// Co-residency: 512 blocks, launch_bounds(256,2), VGPR<=128, LDS 36.9K -> all resident.
__device__ __forceinline__ void gridbar(int* cnt, int target) {
    __syncthreads();                 // all waves' write-through stores retired (vmcnt 0)
    if (threadIdx.x == 0) {
        __hip_atomic_fetch_add(cnt, 1, __ATOMIC_RELAXED, __HIP_MEMORY_SCOPE_AGENT);
        while (__hip_atomic_fetch_add(cnt, 0, __ATOMIC_RELAXED, __HIP_MEMORY_SCOPE_AGENT) < target)
            __builtin_amdgcn_s_sleep(32);
        __atomic_signal_fence(__ATOMIC_SEQ_CST);   // compiler barrier only
    }
    __syncthreads();
}

__global__ __launch_bounds__(256, 2) void gemm2_fused(const u16* __restrict__ Y1,
                                                      const u16* __restrict__ Bw,
                                                      const float* __restrict__ bias,
                                                      const float* __restrict__ P1,
                                                      const float* __restrict__ g1,
                                                      const float* __restrict__ be1,
                                                      float2* __restrict__ BNT1G,
                                                      float* __restrict__ P2,
                                                      const float* __restrict__ g2,
                                                      const float* __restrict__ be2,
                                                      float2* __restrict__ BNT2G,
                                                      float* __restrict__ OUT,
                                                      int* __restrict__ BAR) {
    __shared__ __align__(16) char smemA[36864];
    u16* Al = (u16*)smemA;                       // [128][64]
    u16* Bl = (u16*)(smemA + 16384);             // [128][64]
    u16* T  = (u16*)smemA;                       // [128][136] bf16, TRANSPOSED: [m][j]
    float2* BNT = (float2*)(smemA + 34816);      // 256 x (scale, shift) / reduce scratch
    float* ls  = (float*)(smemA + 34816);
    float* ls2 = (float*)(smemA + 34816 + 1024);
    int tid = threadIdx.x;
    int bid = blockIdx.x;
    int lane = tid & 63, wv = tid >> 6;
    int j0 = (bid >> 1) * 128, m0 = (bid & 1) * 128;
    int l15 = lane & 15, q = lane >> 4;
    int wj = (wv >> 1) * 64, wm = (wv & 1) * 64;

    // ---- phase 0: blocks 0..3 fold BN1 from P1 (P1 from prior kernel) ----
    if (bid < 4) reduce_slice(P1, g1, be1, BNT1G, bid, tid, ls, ls2);
    gridbar(BAR, 512);

    // ---- phase 1: BN1-fused GEMM (KT=256, A=relu(bn1(Y1))) ----
    BNT[tid] = ld_agent_f2(&BNT1G[tid]);         // coherent read of freshly-folded table
    __syncthreads();

    f32x4 acc[4][4];
#pragma unroll
    for (int i = 0; i < 4; ++i)
#pragma unroll
        for (int jj = 0; jj < 4; ++jj) acc[i][jj] = (f32x4){0.f, 0.f, 0.f, 0.f};

    int rbase = wv * 32;
    int lrow = lane >> 3, lchunk = lane & 7;
    int schunk = lchunk ^ lrow;
    const u16* Bg = Bw + (size_t)m0 * 256;

    for (int k0 = 0; k0 < 256; k0 += 64) {
#pragma unroll
        for (int qq = 0; qq < 4; ++qq) {
            int row = rbase + qq * 8;
            async_cp16(&Bl[row * 64], Bg + (size_t)(row + lrow) * 256 + k0 + schunk * 8);
        }
        int c = k0 + lchunk * 8;
        float2 bn[8];
#pragma unroll
        for (int e = 0; e < 8; ++e) bn[e] = BNT[c + e];
#pragma unroll
        for (int qq = 0; qq < 4; ++qq) {
            int row = rbase + qq * 8;
            u16x8 y = *(const u16x8*)&Y1[(size_t)(j0 + row + lrow) * 256 + c];
            u16x8 o;
#pragma unroll
            for (int e = 0; e < 8; ++e)
                o[e] = f2b(fmaxf(b2f(y[e]) * bn[e].x + bn[e].y, 0.f));
            *(u16x8*)&Al[(row + lrow) * 64 + schunk * 8] = o;
        }
        __syncthreads();
#pragma unroll
        for (int ks = 0; ks < 2; ++ks) {
            bf16x8 af[4], bfr[4];
#pragma unroll
            for (int i = 0; i < 4; ++i) {
                int row = wj + i * 16 + l15;
                af[i] = *(const bf16x8*)&Al[row * 64 + ((ks * 4 + q) ^ (l15 & 7)) * 8];
            }
#pragma unroll
            for (int i = 0; i < 4; ++i) {
                int row = wm + i * 16 + l15;
                bfr[i] = *(const bf16x8*)&Bl[row * 64 + ((ks * 4 + q) ^ (l15 & 7)) * 8];
            }
#pragma unroll
            for (int i = 0; i < 4; ++i)
#pragma unroll
                for (int jj = 0; jj < 4; ++jj)
                    acc[i][jj] = __builtin_amdgcn_mfma_f32_16x16x32_bf16(af[i], bfr[jj],
                                                                         acc[i][jj], 0, 0, 0);
        }
        __syncthreads();
    }

    // ---- phase 2: partials (agent stores) + bf16 tile into LDS TRANSPOSED [m][j] ----
#pragma unroll
    for (int jj = 0; jj < 4; ++jj) {
        int ml = wm + jj * 16 + l15;
        float bv = bias[m0 + ml];
        float s = 0.f, s2 = 0.f;
#pragma unroll
        for (int i = 0; i < 4; ++i) {
            int jl = wj + i * 16 + q * 4;
#pragma unroll
            for (int r = 0; r < 4; ++r) {
                float v = acc[i][jj][r] + bv;
                s += v; s2 += v * v;
                T[ml * 136 + (jl + r)] = f2b(v);   // [m][j] for transposed store
            }
        }
        s += __shfl_xor(s, 16); s += __shfl_xor(s, 32);
        s2 += __shfl_xor(s2, 16); s2 += __shfl_xor(s2, 32);
        if (q == 0) {
            size_t prow = (size_t)(bid >> 1) * 2 + (wv >> 1);
            st_agent_f32(&P2[prow * 512 + (m0 + ml)], s);
            st_agent_f32(&P2[prow * 512 + 256 + (m0 + ml)], s2);
        }
    }
    gridbar(BAR, 1024);

    // ---- phase 3: blocks 0..3 fold BN2 from P2 (ls region free; T untouched) ----
    if (bid < 4) reduce_slice(P2, g2, be2, BNT2G, bid, tid, ls, ls2);
    gridbar(BAR, 1536);

    // ---- phase 4: BN2+ReLU from T, transposed store out[b][o][n] ----
    float2* BNTo = (float2*)(smemA + 34816);
    if (tid < 128) BNTo[tid] = ld_agent_f2(&BNT2G[m0 + tid]);
    __syncthreads();
    int ol8 = tid >> 5;              // 0..7
    int j4 = (tid & 31) * 4;         // 0..124
    int bb = j0 >> 13, n0 = j0 & 8191;
#pragma unroll
    for (int it = 0; it < 16; ++it) {
        int ol = it * 8 + ol8;
        float2 bn = BNTo[ol];
        ushort4 h = *(const ushort4*)&T[ol * 136 + j4];
        float4 v;
        v.x = fmaxf(b2f(h.x) * bn.x + bn.y, 0.f);
        v.y = fmaxf(b2f(h.y) * bn.x + bn.y, 0.f);
        v.z = fmaxf(b2f(h.z) * bn.x + bn.y, 0.f);
        v.w = fmaxf(b2f(h.w) * bn.x + bn.y, 0.f);
        *(float4*)&OUT[(size_t)bb * 2097152 + (size_t)(m0 + ol) * 8192 + n0 + j4] = v;
    }
}

extern "C" void kernel_launch(void* const* d_in, const int* in_sizes, int n_in,
                              void* d_out, int out_size, void* d_ws, size_t ws_size,
                              hipStream_t stream) {
    const float* pos1 = (const float*)d_in[0];
    const float* pos2 = (const float*)d_in[1];
    const float* feature1 = (const float*)d_in[2];
    const float* feature2 = (const float*)d_in[3];
    const float* W1 = (const float*)d_in[4];
    const float* b1 = (const float*)d_in[5];
    const float* g1 = (const float*)d_in[6];
    const float* be1 = (const float*)d_in[7];
    const float* W2 = (const float*)d_in[8];
    const float* b2 = (const float*)d_in[9];
    const float* g2 = (const float*)d_in[10];
    const float* be2 = (const float*)d_in[11];

    char* ws = (char*)d_ws;
    int*    IDX   = (int*)(ws + 0);                 // 393216 B
    float*  WGT   = (float*)(ws + 393216);          // 393216 B
    u16*    W1B   = (u16*)(ws + 786432);            // 196608 B
    u16*    W2B   = (u16*)(ws + 983040);            // 131072 B (contiguous after W1B)
    float2* BNT1G = (float2*)(ws + 1114112);        // 2048 B folded BN1 (scale, shift)
    float2* BNT2G = (float2*)(ws + 1116160);        // 2048 B folded BN2
    u16*    F2T   = (u16*)(ws + 1118208);           // 4 MiB  [4][2048][256]
    u16*    F1T   = (u16*)(ws + 5312512);           // 8 MiB  [4][8192][128]
    u16*    Y1    = (u16*)(ws + 13701120);          // 16 MiB [32768][256]
    u16*    INTERP= (u16*)(ws + 30478336);          // 16 MiB [32768][256] bf16
    float*  P1    = (float*)(ws + 47255552);        // 1 MiB [512][512] partials gemm1
    float*  P2    = (float*)(ws + 48304128);        // 1 MiB partials gemm2
    int*    BAR   = (int*)(ws + 49352704);          // grid-barrier counter
    float*  OUT   = (float*)d_out;

    prep_kernel<<<NB_NN + NB_CVT + NB_T2 + NB_T1, 256, 0, stream>>>(
        W1, W2, W1B, feature2, F2T, feature1, F1T, pos1, pos2, IDX, WGT);
    interp_kernel<<<2048, 256, 0, stream>>>(F2T, IDX, WGT, INTERP);
    gemm1_kernel<<<dim3(256, 2), 256, 0, stream>>>(INTERP, F1T, W1B, b1, Y1, P1, BAR);
    gemm2_fused<<<512, 256, 0, stream>>>(Y1, W2B, b2, P1, g1, be1, BNT1G,
                                         P2, g2, be2, BNT2G, OUT, BAR);
}

// Round 4
// 210.071 us; speedup vs baseline: 3.8396x; 1.2348x over previous
//
#include <hip/hip_runtime.h>
#include <hip/hip_bf16.h>
#include <cstdint>

typedef unsigned short u16;
typedef unsigned int u32;
typedef unsigned long long u64;
typedef __bf16 bf16x8 __attribute__((ext_vector_type(8)));
typedef float f32x4 __attribute__((ext_vector_type(4)));
typedef u16 u16x8 __attribute__((ext_vector_type(8)));

#define FPSCALE 1048576.0f          // 2^20 fixed-point for BN stats
#define FPINV   (1.0f / 1048576.0f)

// ---------- helpers ----------
__device__ __forceinline__ u16 f2b(float f) {          // fp32 -> bf16 RNE
    unsigned int u = __float_as_uint(f);
    u += 0x7fffu + ((u >> 16) & 1u);
    return (u16)(u >> 16);
}
__device__ __forceinline__ float b2f(u16 h) {
    return __uint_as_float(((unsigned int)h) << 16);
}
__device__ __forceinline__ void async_cp16(void* lds, const void* g) {
    __builtin_amdgcn_global_load_lds((const __attribute__((address_space(1))) void*)g,
                                     (__attribute__((address_space(3))) void*)lds, 16, 0, 0);
}
__device__ __forceinline__ u64 ld_agent_u64(const u64* p) {
    return __hip_atomic_load(p, __ATOMIC_RELAXED, __HIP_MEMORY_SCOPE_AGENT);
}
// monotone unsigned mapping of float bits (order-preserving, EXACT)
__device__ __forceinline__ u32 fmono(float f) {
    u32 u = __float_as_uint(f);
    return u ^ (((u32)((int)u >> 31)) | 0x80000000u);
}
__device__ __forceinline__ u64 shfl_xor_u64(u64 v, int mask) {
    u32 lo = (u32)v, hi = (u32)(v >> 32);
    lo = (u32)__shfl_xor((int)lo, mask);
    hi = (u32)__shfl_xor((int)hi, mask);
    return ((u64)hi << 32) | lo;
}
// insert exact key into descending top-3 (keys unique: idx field breaks ties)
__device__ __forceinline__ void ins3(u64 k, u64& k0, u64& k1, u64& k2) {
    bool c0 = k > k0, c1 = k > k1, c2 = k > k2;
    k2 = c1 ? k1 : (c2 ? k : k2);
    k1 = c0 ? k0 : (c1 ? k : k1);
    k0 = c0 ? k : k0;
}
// padded pk index: one float4 pad every 64 entries (chunk groups on distinct banks)
__device__ __forceinline__ int pkix(int i) { return i + (i >> 6); }

// ================= prep kernel: three_nn FIRST, then cvt + transposes =================
#define NB_NN  1024
#define NB_CVT 160
#define NB_T2  512
#define NB_T1  1024

__global__ __launch_bounds__(256, 6) void prep_kernel(const float* __restrict__ w1,
                                                      const float* __restrict__ w2,
                                                      u16* __restrict__ wb,
                                                      const float* __restrict__ feature2,
                                                      u16* __restrict__ f2t,
                                                      const float* __restrict__ feature1,
                                                      u16* __restrict__ f1t,
                                                      const float* __restrict__ pos1,
                                                      const float* __restrict__ pos2,
                                                      int* __restrict__ idx_out,
                                                      float* __restrict__ w_out,
                                                      u64* __restrict__ SZ) {
    __shared__ __align__(16) char smem[19712];   // 16640 pk-half + 3072 warr
    int bi = blockIdx.x;
    int tid = threadIdx.x;

    if (bi >= NB_NN) {
        int ci = bi - NB_NN;
        if (ci >= NB_CVT + NB_T2 + NB_T1) {
            // ---- zero stats block: S1[512] | S2[512] | BAR (per graph replay) ----
            u64* S = SZ + (size_t)tid * 4;
            S[0] = 0; S[1] = 0; S[2] = 0; S[3] = 0;
            if (tid == 0) *(int*)(SZ + 1024) = 0;
            return;
        }
        if (ci < NB_CVT) {
            int i = ci * 256 + tid;
            if (i < 40960) {
                const float* src = (i < 24576) ? w1 : w2;
                int k = (i < 24576) ? i : (i - 24576);
                float4 v = *(const float4*)&src[(size_t)k * 4];
                ushort4 o;
                o.x = f2b(v.x); o.y = f2b(v.y); o.z = f2b(v.z); o.w = f2b(v.w);
                *(ushort4*)&wb[(size_t)i * 4] = o;
            }
            return;
        }
        // ---- transpose [B][C][S] -> [B][S][C] bf16 ----
        float (*t)[65] = (float (*)[65])smem;
        const float* in; u16* out; int C, S, s0, c0, b;
        if (ci < NB_CVT + NB_T2) {
            int lin = ci - NB_CVT;
            C = 256; S = 2048; in = feature2; out = f2t;
            s0 = (lin & 31) * 64; c0 = ((lin >> 5) & 3) * 64; b = lin >> 7;
        } else {
            int lin = ci - NB_CVT - NB_T2;
            C = 128; S = 8192; in = feature1; out = f1t;
            s0 = (lin & 127) * 64; c0 = ((lin >> 7) & 1) * 64; b = lin >> 8;
        }
        const float* ib = in + (size_t)b * C * S;
        u16* ob = out + (size_t)b * S * C;
        int col = tid & 63, r0 = tid >> 6;
#pragma unroll
        for (int p = 0; p < 16; ++p) {
            int c = p * 4 + r0;
            t[c][col] = ib[(size_t)(c0 + c) * S + s0 + col];
        }
        __syncthreads();
#pragma unroll
        for (int p = 0; p < 16; ++p) {
            int s = p * 4 + r0;
            ob[(size_t)(s0 + s) * C + c0 + col] = f2b(t[col][s]);
        }
        return;
    }

    // ---- three_nn: 32 queries/block; thread handles queries p, p+16 ----
    float4* pk = (float4*)smem;                          // padded: 1040 float4 = 16640 B
    u64* warr = (u64*)(smem + 16640);                    // [4 waves][16 p][2 t][3]
    int j0 = bi * 32;
    int b = j0 >> 13;
    const float* p2 = pos2 + (size_t)b * 3 * 2048;
    int p = tid & 15, ck = tid >> 4;
    int wv = tid >> 6, lane = tid & 63;
    const float* p1 = pos1 + (size_t)b * 3 * 8192;
    float qx[2], qy[2], qz[2];
#pragma unroll
    for (int t = 0; t < 2; ++t) {
        int n = (j0 & 8191) + p + t * 16;
        qx[t] = p1[n]; qy[t] = p1[8192 + n]; qz[t] = p1[16384 + n];
    }
    u64 key[2][3];
#pragma unroll
    for (int t = 0; t < 2; ++t) { key[t][0] = 0; key[t][1] = 0; key[t][2] = 0; }

    for (int half = 0; half < 2; ++half) {
        int hbase = half * 1024;
        for (int i = tid; i < 1024; i += 256) {
            int s = hbase + i;
            float x = p2[s], y = p2[2048 + s], z = p2[4096 + s];
            pk[pkix(i)] = make_float4(x, y, z, -0.5f * (x * x + y * y + z * z));
        }
        __syncthreads();

        float g[2][3]; int id[2][3];
#pragma unroll
        for (int t = 0; t < 2; ++t) {
            g[t][0] = -3.4e38f; g[t][1] = -3.4e38f; g[t][2] = -3.4e38f;
            id[t][0] = 0; id[t][1] = 0; id[t][2] = 0;
        }
        int sb = ck * 64;
        const float4* pc = pk + pkix(sb);
#pragma unroll 2
        for (int it = 0; it < 64; ++it) {
            float4 cd = pc[it];
            int s = sb + it;
#pragma unroll
            for (int t = 0; t < 2; ++t) {
                float tv = fmaf(qx[t], cd.x, fmaf(qy[t], cd.y, fmaf(qz[t], cd.z, cd.w)));
                bool c0 = tv > g[t][0], c1 = tv > g[t][1], c2 = tv > g[t][2];
                float o0 = g[t][0], o1 = g[t][1];
                g[t][2] = __builtin_amdgcn_fmed3f(tv, o1, g[t][2]);
                g[t][1] = __builtin_amdgcn_fmed3f(tv, o0, o1);
                g[t][0] = fmaxf(o0, tv);
                id[t][2] = c1 ? id[t][1] : (c2 ? s : id[t][2]);
                id[t][1] = c0 ? id[t][0] : (c1 ? s : id[t][1]);
                id[t][0] = c0 ? s : id[t][0];
            }
        }
        __syncthreads();   // reads done before next half restages

#pragma unroll
        for (int t = 0; t < 2; ++t) {
#pragma unroll
            for (int r = 0; r < 3; ++r)
                ins3(((u64)fmono(g[t][r]) << 32) | (u64)(2047 - (hbase + id[t][r])),
                     key[t][0], key[t][1], key[t][2]);
        }
    }

    // in-wave merge across the 4 chunk-groups (lane>>4)
#pragma unroll
    for (int mask = 16; mask <= 32; mask <<= 1) {
#pragma unroll
        for (int t = 0; t < 2; ++t) {
            u64 m0 = shfl_xor_u64(key[t][0], mask);
            u64 m1 = shfl_xor_u64(key[t][1], mask);
            u64 m2 = shfl_xor_u64(key[t][2], mask);
            ins3(m0, key[t][0], key[t][1], key[t][2]);
            ins3(m1, key[t][0], key[t][1], key[t][2]);
            ins3(m2, key[t][0], key[t][1], key[t][2]);
        }
    }
    if (lane < 16) {
        u64* wr = &warr[(wv * 16 + p) * 6];
#pragma unroll
        for (int t = 0; t < 2; ++t) {
            wr[t * 3 + 0] = key[t][0]; wr[t * 3 + 1] = key[t][1]; wr[t * 3 + 2] = key[t][2];
        }
    }
    __syncthreads();
    if (tid < 32) {
        int pp = tid & 15, t = tid >> 4;
        const u64* w0 = &warr[pp * 6 + t * 3];
        u64 k0 = w0[0], k1 = w0[1], k2 = w0[2];
#pragma unroll
        for (int w = 1; w < 4; ++w) {
            const u64* wr = &warr[(w * 16 + pp) * 6 + t * 3];
            ins3(wr[0], k0, k1, k2);
            ins3(wr[1], k0, k1, k2);
            ins3(wr[2], k0, k1, k2);
        }
        int s0 = 2047 - (int)(k0 & 0xFFFFFFFFu);
        int s1 = 2047 - (int)(k1 & 0xFFFFFFFFu);
        int s2 = 2047 - (int)(k2 & 0xFFFFFFFFu);
        int j = j0 + pp + t * 16;
        int n = j & 8191;
        float x1 = p1[n], y1 = p1[8192 + n], z1 = p1[16384 + n];
        float n1 = x1 * x1 + y1 * y1 + z1 * z1;
        float X0 = p2[s0], Y0 = p2[2048 + s0], Z0 = p2[4096 + s0];
        float X1 = p2[s1], Y1v = p2[2048 + s1], Z1 = p2[4096 + s1];
        float X2 = p2[s2], Y2v = p2[2048 + s2], Z2 = p2[4096 + s2];
        float t0 = x1 * X0 + y1 * Y0 + z1 * Z0 - 0.5f * (X0 * X0 + Y0 * Y0 + Z0 * Z0);
        float t1 = x1 * X1 + y1 * Y1v + z1 * Z1 - 0.5f * (X1 * X1 + Y1v * Y1v + Z1 * Z1);
        float t2 = x1 * X2 + y1 * Y2v + z1 * Z2 - 0.5f * (X2 * X2 + Y2v * Y2v + Z2 * Z2);
        float d0 = fmaxf(fmaf(-2.f, t0, n1), 1e-10f);
        float d1 = fmaxf(fmaf(-2.f, t1, n1), 1e-10f);
        float d2 = fmaxf(fmaf(-2.f, t2, n1), 1e-10f);
        float w0v = 1.f / d0, w1v = 1.f / d1, w2v = 1.f / d2;
        float inv = 1.f / (w0v + w1v + w2v);
        idx_out[j * 3] = s0; idx_out[j * 3 + 1] = s1; idx_out[j * 3 + 2] = s2;
        w_out[j * 3] = w0v * inv; w_out[j * 3 + 1] = w1v * inv; w_out[j * 3 + 2] = w2v * inv;
    }
}

// ---------- interp: gather 3 rows of F2T, weighted sum -> bf16 [32768][256] ----------
__global__ __launch_bounds__(256, 8) void interp_kernel(const u16* __restrict__ f2t,
                                                        const int* __restrict__ idx,
                                                        const float* __restrict__ wgt,
                                                        u16* __restrict__ out) {
    int tid = threadIdx.x;
    int j = blockIdx.x * 16 + (tid >> 4);        // 16 rows/block, 16 threads/row
    int c0 = (tid & 15) * 16;                    // 16 channels/thread
    int b = j >> 13;
    const u16* fb = f2t + (size_t)b * 2048 * 256;
    const u16* r0 = fb + (size_t)idx[j * 3 + 0] * 256 + c0;
    const u16* r1 = fb + (size_t)idx[j * 3 + 1] * 256 + c0;
    const u16* r2 = fb + (size_t)idx[j * 3 + 2] * 256 + c0;
    float w0 = wgt[j * 3 + 0], w1 = wgt[j * 3 + 1], w2 = wgt[j * 3 + 2];
    u16* ob = out + (size_t)j * 256 + c0;
#pragma unroll
    for (int cc = 0; cc < 2; ++cc) {
        u16x8 v0 = *(const u16x8*)(r0 + cc * 8);
        u16x8 v1 = *(const u16x8*)(r1 + cc * 8);
        u16x8 v2 = *(const u16x8*)(r2 + cc * 8);
        u16x8 o;
#pragma unroll
        for (int e = 0; e < 8; ++e)
            o[e] = f2b(w0 * b2f(v0[e]) + w1 * b2f(v1[e]) + w2 * b2f(v2[e]));
        *(u16x8*)(ob + cc * 8) = o;
    }
}

// ---------- GEMM1: Yb[j][m] = bf16(sum_k A[j][k]*Bw[m][k] + bias[m]) ----------
// BN1 stats: fixed-point i64 atomicAdd into S1[512] (sum | sumsq). Deterministic
// (integer adds commute); quantization 2^-20 per contribution ~ 3e-9 on the mean.
__global__ __launch_bounds__(256, 2) void gemm1_kernel(const u16* __restrict__ A1,
                                                       const u16* __restrict__ A2,
                                                       const u16* __restrict__ Bw,
                                                       const float* __restrict__ bias,
                                                       u16* __restrict__ Yb,
                                                       u64* __restrict__ S1) {
    __shared__ __align__(16) char smemA[36864];
    u16* Al = (u16*)smemA;                       // [128][64], k-loop (swizzled cols)
    u16* Bl = (u16*)(smemA + 16384);             // [128][64], k-loop (swizzled cols)
    u16* T  = (u16*)smemA;                       // [128][136] epilogue bounce (overlays Al/Bl)
    int tid = threadIdx.x;
    int lane = tid & 63, wv = tid >> 6;
    int j0 = blockIdx.x * 128, m0 = blockIdx.y * 128;
    int l15 = lane & 15, q = lane >> 4;
    int wj = (wv >> 1) * 64, wm = (wv & 1) * 64;
    f32x4 acc[4][4];
#pragma unroll
    for (int i = 0; i < 4; ++i)
#pragma unroll
        for (int jj = 0; jj < 4; ++jj) acc[i][jj] = (f32x4){0.f, 0.f, 0.f, 0.f};

    int rbase = wv * 32;
    int lrow = lane >> 3, lchunk = lane & 7;
    int schunk = lchunk ^ lrow;                  // swizzled chunk for staging
    const u16* Bg = Bw + (size_t)m0 * 384;

    for (int k0 = 0; k0 < 384; k0 += 64) {
#pragma unroll
        for (int qq = 0; qq < 4; ++qq) {
            int row = rbase + qq * 8;
            async_cp16(&Bl[row * 64], Bg + (size_t)(row + lrow) * 384 + k0 + schunk * 8);
        }
        const u16* src; int str;
        if (k0 < 256) { src = A1 + (size_t)j0 * 256 + k0;         str = 256; }
        else          { src = A2 + (size_t)j0 * 128 + (k0 - 256); str = 128; }
#pragma unroll
        for (int qq = 0; qq < 4; ++qq) {
            int row = rbase + qq * 8;
            async_cp16(&Al[row * 64], src + (size_t)(row + lrow) * str + schunk * 8);
        }
        __syncthreads();
#pragma unroll
        for (int ks = 0; ks < 2; ++ks) {
            bf16x8 af[4], bfr[4];
#pragma unroll
            for (int i = 0; i < 4; ++i) {
                int row = wj + i * 16 + l15;
                af[i] = *(const bf16x8*)&Al[row * 64 + ((ks * 4 + q) ^ (l15 & 7)) * 8];
            }
#pragma unroll
            for (int i = 0; i < 4; ++i) {
                int row = wm + i * 16 + l15;
                bfr[i] = *(const bf16x8*)&Bl[row * 64 + ((ks * 4 + q) ^ (l15 & 7)) * 8];
            }
#pragma unroll
            for (int i = 0; i < 4; ++i)
#pragma unroll
                for (int jj = 0; jj < 4; ++jj)
                    acc[i][jj] = __builtin_amdgcn_mfma_f32_16x16x32_bf16(af[i], bfr[jj],
                                                                         acc[i][jj], 0, 0, 0);
        }
        __syncthreads();
    }
    // epilogue: per-channel fixed-point stat atomics + bf16 tile into LDS
#pragma unroll
    for (int jj = 0; jj < 4; ++jj) {
        int ml = wm + jj * 16 + l15;
        float bv = bias[m0 + ml];
        float s = 0.f, s2 = 0.f;
#pragma unroll
        for (int i = 0; i < 4; ++i) {
            int jl = wj + i * 16 + q * 4;
#pragma unroll
            for (int r = 0; r < 4; ++r) {
                float v = acc[i][jj][r] + bv;
                s += v; s2 += v * v;
                T[(jl + r) * 136 + ml] = f2b(v);
            }
        }
        s += __shfl_xor(s, 16); s += __shfl_xor(s, 32);
        s2 += __shfl_xor(s2, 16); s2 += __shfl_xor(s2, 32);
        if (q == 0) {
            atomicAdd(&S1[m0 + ml], (u64)(long long)llrintf(s * FPSCALE));
            atomicAdd(&S1[256 + m0 + ml], (u64)(long long)llrintf(s2 * FPSCALE));
        }
    }
    __syncthreads();
#pragma unroll
    for (int it = 0; it < 8; ++it) {
        int jl = it * 16 + wv * 4 + q;
        u16x8 v = *(const u16x8*)&T[jl * 136 + l15 * 8];
        *(u16x8*)&Yb[(size_t)(j0 + jl) * 256 + m0 + l15 * 8] = v;
    }
}

// ---------- gemm2_fused: local BN1 fold -> fused GEMM2 -> ONE barrier -> BN2+store ----------
// R3 post-mortem: 3 barriers with RMW-spin = same-address atomic RMW storm (600/us on one
// line) -> ~25us backlog each. Now: stats via i64 atomicAdd (no reduce phases), BN folds
// computed locally per block, ONE barrier whose poll is a relaxed atomic LOAD (reads don't
// serialize; relaxed emits no invalidates). Arrive = one RMW per block (512 total).
__device__ __forceinline__ void gridbar(int* cnt, int target) {
    __syncthreads();                 // vmcnt(0): this block's stat atomics completed
    if (threadIdx.x == 0) {
        __hip_atomic_fetch_add(cnt, 1, __ATOMIC_RELAXED, __HIP_MEMORY_SCOPE_AGENT);
        while (__hip_atomic_load(cnt, __ATOMIC_RELAXED, __HIP_MEMORY_SCOPE_AGENT) < target)
            __builtin_amdgcn_s_sleep(16);
        __atomic_signal_fence(__ATOMIC_SEQ_CST);   // compiler barrier only
    }
    __syncthreads();
}

__global__ __launch_bounds__(256, 2) void gemm2_fused(const u16* __restrict__ Y1,
                                                      const u16* __restrict__ Bw,
                                                      const float* __restrict__ bias,
                                                      const u64* __restrict__ S1,
                                                      const float* __restrict__ g1,
                                                      const float* __restrict__ be1,
                                                      u64* __restrict__ S2,
                                                      const float* __restrict__ g2,
                                                      const float* __restrict__ be2,
                                                      float* __restrict__ OUT,
                                                      int* __restrict__ BAR) {
    __shared__ __align__(16) char smemA[36864];
    u16* Al = (u16*)smemA;                       // [128][64]
    u16* Bl = (u16*)(smemA + 16384);             // [128][64]
    u16* T  = (u16*)smemA;                       // [128][136] bf16, TRANSPOSED: [m][j]
    float2* BNT = (float2*)(smemA + 34816);      // 256 x (scale, shift)
    int tid = threadIdx.x;
    int bid = blockIdx.x;
    int lane = tid & 63, wv = tid >> 6;
    int j0 = (bid >> 1) * 128, m0 = (bid & 1) * 128;
    int l15 = lane & 15, q = lane >> 4;
    int wj = (wv >> 1) * 64, wm = (wv & 1) * 64;

    // ---- phase 0: fold BN1 locally (S1 complete: written by the previous kernel) ----
    {
        long long su = (long long)S1[tid];
        long long sq = (long long)S1[256 + tid];
        float fs  = (float)su * FPINV;
        float fs2 = (float)sq * FPINV;
        const float inv = 1.f / 32768.f;
        float mean = fs * inv;
        float var = fs2 * inv - mean * mean;
        float a = g1[tid] * rsqrtf(var + 1e-5f);
        BNT[tid] = make_float2(a, be1[tid] - mean * a);
    }
    __syncthreads();

    // ---- phase 1: BN1-fused GEMM (KT=256, A=relu(bn1(Y1))) ----
    f32x4 acc[4][4];
#pragma unroll
    for (int i = 0; i < 4; ++i)
#pragma unroll
        for (int jj = 0; jj < 4; ++jj) acc[i][jj] = (f32x4){0.f, 0.f, 0.f, 0.f};

    int rbase = wv * 32;
    int lrow = lane >> 3, lchunk = lane & 7;
    int schunk = lchunk ^ lrow;
    const u16* Bg = Bw + (size_t)m0 * 256;

    for (int k0 = 0; k0 < 256; k0 += 64) {
#pragma unroll
        for (int qq = 0; qq < 4; ++qq) {
            int row = rbase + qq * 8;
            async_cp16(&Bl[row * 64], Bg + (size_t)(row + lrow) * 256 + k0 + schunk * 8);
        }
        int c = k0 + lchunk * 8;
        float2 bn[8];
#pragma unroll
        for (int e = 0; e < 8; ++e) bn[e] = BNT[c + e];
#pragma unroll
        for (int qq = 0; qq < 4; ++qq) {
            int row = rbase + qq * 8;
            u16x8 y = *(const u16x8*)&Y1[(size_t)(j0 + row + lrow) * 256 + c];
            u16x8 o;
#pragma unroll
            for (int e = 0; e < 8; ++e)
                o[e] = f2b(fmaxf(b2f(y[e]) * bn[e].x + bn[e].y, 0.f));
            *(u16x8*)&Al[(row + lrow) * 64 + schunk * 8] = o;
        }
        __syncthreads();
#pragma unroll
        for (int ks = 0; ks < 2; ++ks) {
            bf16x8 af[4], bfr[4];
#pragma unroll
            for (int i = 0; i < 4; ++i) {
                int row = wj + i * 16 + l15;
                af[i] = *(const bf16x8*)&Al[row * 64 + ((ks * 4 + q) ^ (l15 & 7)) * 8];
            }
#pragma unroll
            for (int i = 0; i < 4; ++i) {
                int row = wm + i * 16 + l15;
                bfr[i] = *(const bf16x8*)&Bl[row * 64 + ((ks * 4 + q) ^ (l15 & 7)) * 8];
            }
#pragma unroll
            for (int i = 0; i < 4; ++i)
#pragma unroll
                for (int jj = 0; jj < 4; ++jj)
                    acc[i][jj] = __builtin_amdgcn_mfma_f32_16x16x32_bf16(af[i], bfr[jj],
                                                                         acc[i][jj], 0, 0, 0);
        }
        __syncthreads();
    }

    // ---- phase 2: stat atomics + bf16 tile into LDS TRANSPOSED [m][j] ----
#pragma unroll
    for (int jj = 0; jj < 4; ++jj) {
        int ml = wm + jj * 16 + l15;
        float bv = bias[m0 + ml];
        float s = 0.f, s2 = 0.f;
#pragma unroll
        for (int i = 0; i < 4; ++i) {
            int jl = wj + i * 16 + q * 4;
#pragma unroll
            for (int r = 0; r < 4; ++r) {
                float v = acc[i][jj][r] + bv;
                s += v; s2 += v * v;
                T[ml * 136 + (jl + r)] = f2b(v);   // [m][j] for transposed store
            }
        }
        s += __shfl_xor(s, 16); s += __shfl_xor(s, 32);
        s2 += __shfl_xor(s2, 16); s2 += __shfl_xor(s2, 32);
        if (q == 0) {
            atomicAdd(&S2[m0 + ml], (u64)(long long)llrintf(s * FPSCALE));
            atomicAdd(&S2[256 + m0 + ml], (u64)(long long)llrintf(s2 * FPSCALE));
        }
    }
    gridbar(BAR, 512);               // the ONE grid barrier

    // ---- phase 3: fold BN2 locally for this block's 128 channels ----
    if (tid < 128) {
        int c = m0 + tid;
        long long su = (long long)ld_agent_u64(&S2[c]);
        long long sq = (long long)ld_agent_u64(&S2[256 + c]);
        float fs  = (float)su * FPINV;
        float fs2 = (float)sq * FPINV;
        const float inv = 1.f / 32768.f;
        float mean = fs * inv;
        float var = fs2 * inv - mean * mean;
        float a = g2[c] * rsqrtf(var + 1e-5f);
        BNT[tid] = make_float2(a, be2[c] - mean * a);
    }
    __syncthreads();

    // ---- phase 4: BN2+ReLU from T, transposed store out[b][o][n] ----
    int ol8 = tid >> 5;              // 0..7
    int j4 = (tid & 31) * 4;         // 0..124
    int bb = j0 >> 13, n0 = j0 & 8191;
#pragma unroll
    for (int it = 0; it < 16; ++it) {
        int ol = it * 8 + ol8;
        float2 bn = BNT[ol];
        ushort4 h = *(const ushort4*)&T[ol * 136 + j4];
        float4 v;
        v.x = fmaxf(b2f(h.x) * bn.x + bn.y, 0.f);
        v.y = fmaxf(b2f(h.y) * bn.x + bn.y, 0.f);
        v.z = fmaxf(b2f(h.z) * bn.x + bn.y, 0.f);
        v.w = fmaxf(b2f(h.w) * bn.x + bn.y, 0.f);
        *(float4*)&OUT[(size_t)bb * 2097152 + (size_t)(m0 + ol) * 8192 + n0 + j4] = v;
    }
}

extern "C" void kernel_launch(void* const* d_in, const int* in_sizes, int n_in,
                              void* d_out, int out_size, void* d_ws, size_t ws_size,
                              hipStream_t stream) {
    const float* pos1 = (const float*)d_in[0];
    const float* pos2 = (const float*)d_in[1];
    const float* feature1 = (const float*)d_in[2];
    const float* feature2 = (const float*)d_in[3];
    const float* W1 = (const float*)d_in[4];
    const float* b1 = (const float*)d_in[5];
    const float* g1 = (const float*)d_in[6];
    const float* be1 = (const float*)d_in[7];
    const float* W2 = (const float*)d_in[8];
    const float* b2 = (const float*)d_in[9];
    const float* g2 = (const float*)d_in[10];
    const float* be2 = (const float*)d_in[11];

    char* ws = (char*)d_ws;
    int*    IDX   = (int*)(ws + 0);                 // 393216 B
    float*  WGT   = (float*)(ws + 393216);          // 393216 B
    u16*    W1B   = (u16*)(ws + 786432);            // 196608 B
    u16*    W2B   = (u16*)(ws + 983040);            // 131072 B (contiguous after W1B)
    u16*    F2T   = (u16*)(ws + 1118208);           // 4 MiB  [4][2048][256]
    u16*    F1T   = (u16*)(ws + 5312512);           // 8 MiB  [4][8192][128]
    u16*    Y1    = (u16*)(ws + 13701120);          // 16 MiB [32768][256]
    u16*    INTERP= (u16*)(ws + 30478336);          // 16 MiB [32768][256] bf16
    u64*    SSTAT = (u64*)(ws + 47255552);          // S1[512] | S2[512] | BAR
    u64*    S1    = SSTAT;
    u64*    S2    = SSTAT + 512;
    int*    BAR   = (int*)(SSTAT + 1024);
    float*  OUT   = (float*)d_out;

    prep_kernel<<<NB_NN + NB_CVT + NB_T2 + NB_T1 + 1, 256, 0, stream>>>(
        W1, W2, W1B, feature2, F2T, feature1, F1T, pos1, pos2, IDX, WGT, SSTAT);
    interp_kernel<<<2048, 256, 0, stream>>>(F2T, IDX, WGT, INTERP);
    gemm1_kernel<<<dim3(256, 2), 256, 0, stream>>>(INTERP, F1T, W1B, b1, Y1, S1);
    gemm2_fused<<<512, 256, 0, stream>>>(Y1, W2B, b2, S1, g1, be1,
                                         S2, g2, be2, OUT, BAR);
}

// Round 5
// 188.411 us; speedup vs baseline: 4.2810x; 1.1150x over previous
//
#include <hip/hip_runtime.h>
#include <hip/hip_bf16.h>
#include <cstdint>

typedef unsigned short u16;
typedef unsigned int u32;
typedef unsigned long long u64;
typedef __bf16 bf16x8 __attribute__((ext_vector_type(8)));
typedef float f32x4 __attribute__((ext_vector_type(4)));
typedef u16 u16x8 __attribute__((ext_vector_type(8)));

#define FPSCALE 1048576.0f          // 2^20 fixed-point for BN stats
#define FPINV   (1.0f / 1048576.0f)
#define NSLICE 16                   // atomic-contention slices (32 RMWs/address)

// ---------- helpers ----------
__device__ __forceinline__ u16 f2b(float f) {          // fp32 -> bf16 RNE
    unsigned int u = __float_as_uint(f);
    u += 0x7fffu + ((u >> 16) & 1u);
    return (u16)(u >> 16);
}
__device__ __forceinline__ float b2f(u16 h) {
    return __uint_as_float(((unsigned int)h) << 16);
}
__device__ __forceinline__ void async_cp16(void* lds, const void* g) {
    __builtin_amdgcn_global_load_lds((const __attribute__((address_space(1))) void*)g,
                                     (__attribute__((address_space(3))) void*)lds, 16, 0, 0);
}
__device__ __forceinline__ u64 ld_agent_u64(const u64* p) {
    return __hip_atomic_load(p, __ATOMIC_RELAXED, __HIP_MEMORY_SCOPE_AGENT);
}
// monotone unsigned mapping of float bits (order-preserving, EXACT)
__device__ __forceinline__ u32 fmono(float f) {
    u32 u = __float_as_uint(f);
    return u ^ (((u32)((int)u >> 31)) | 0x80000000u);
}
__device__ __forceinline__ u64 shfl_xor_u64(u64 v, int mask) {
    u32 lo = (u32)v, hi = (u32)(v >> 32);
    lo = (u32)__shfl_xor((int)lo, mask);
    hi = (u32)__shfl_xor((int)hi, mask);
    return ((u64)hi << 32) | lo;
}
// insert exact key into descending top-3 (keys unique: idx field breaks ties)
__device__ __forceinline__ void ins3(u64 k, u64& k0, u64& k1, u64& k2) {
    bool c0 = k > k0, c1 = k > k1, c2 = k > k2;
    k2 = c1 ? k1 : (c2 ? k : k2);
    k1 = c0 ? k0 : (c1 ? k : k1);
    k0 = c0 ? k : k0;
}
// padded pk index: one float4 pad every 64 entries (chunk groups on distinct banks)
__device__ __forceinline__ int pkix(int i) { return i + (i >> 6); }

// ================= prep kernel: three_nn FIRST, then cvt + transposes =================
#define NB_NN  1024
#define NB_CVT 160
#define NB_T2  512
#define NB_T1  1024

__global__ __launch_bounds__(256, 6) void prep_kernel(const float* __restrict__ w1,
                                                      const float* __restrict__ w2,
                                                      u16* __restrict__ wb,
                                                      const float* __restrict__ feature2,
                                                      u16* __restrict__ f2t,
                                                      const float* __restrict__ feature1,
                                                      u16* __restrict__ f1t,
                                                      const float* __restrict__ pos1,
                                                      const float* __restrict__ pos2,
                                                      int* __restrict__ idx_out,
                                                      float* __restrict__ w_out,
                                                      u64* __restrict__ SZ) {
    __shared__ __align__(16) char smem[19712];   // 16640 pk-half + 3072 warr
    int bi = blockIdx.x;
    int tid = threadIdx.x;

    if (bi >= NB_NN) {
        int ci = bi - NB_NN;
        if (ci >= NB_CVT + NB_T2 + NB_T1) {
            // ---- zero stats: S1[16][512] | S2[16][512] | BAR (per graph replay) ----
            for (int i = tid; i < 2 * NSLICE * 512; i += 256) SZ[i] = 0;
            if (tid == 0) *(int*)(SZ + 2 * NSLICE * 512) = 0;
            return;
        }
        if (ci < NB_CVT) {
            int i = ci * 256 + tid;
            if (i < 40960) {
                const float* src = (i < 24576) ? w1 : w2;
                int k = (i < 24576) ? i : (i - 24576);
                float4 v = *(const float4*)&src[(size_t)k * 4];
                ushort4 o;
                o.x = f2b(v.x); o.y = f2b(v.y); o.z = f2b(v.z); o.w = f2b(v.w);
                *(ushort4*)&wb[(size_t)i * 4] = o;
            }
            return;
        }
        // ---- transpose [B][C][S] -> [B][S][C] bf16 ----
        float (*t)[65] = (float (*)[65])smem;
        const float* in; u16* out; int C, S, s0, c0, b;
        if (ci < NB_CVT + NB_T2) {
            int lin = ci - NB_CVT;
            C = 256; S = 2048; in = feature2; out = f2t;
            s0 = (lin & 31) * 64; c0 = ((lin >> 5) & 3) * 64; b = lin >> 7;
        } else {
            int lin = ci - NB_CVT - NB_T2;
            C = 128; S = 8192; in = feature1; out = f1t;
            s0 = (lin & 127) * 64; c0 = ((lin >> 7) & 1) * 64; b = lin >> 8;
        }
        const float* ib = in + (size_t)b * C * S;
        u16* ob = out + (size_t)b * S * C;
        int col = tid & 63, r0 = tid >> 6;
#pragma unroll
        for (int p = 0; p < 16; ++p) {
            int c = p * 4 + r0;
            t[c][col] = ib[(size_t)(c0 + c) * S + s0 + col];
        }
        __syncthreads();
#pragma unroll
        for (int p = 0; p < 16; ++p) {
            int s = p * 4 + r0;
            ob[(size_t)(s0 + s) * C + c0 + col] = f2b(t[col][s]);
        }
        return;
    }

    // ---- three_nn: 32 queries/block; thread handles queries p, p+16 ----
    float4* pk = (float4*)smem;                          // padded: 1040 float4 = 16640 B
    u64* warr = (u64*)(smem + 16640);                    // [4 waves][16 p][2 t][3]
    int j0 = bi * 32;
    int b = j0 >> 13;
    const float* p2 = pos2 + (size_t)b * 3 * 2048;
    int p = tid & 15, ck = tid >> 4;
    int wv = tid >> 6, lane = tid & 63;
    const float* p1 = pos1 + (size_t)b * 3 * 8192;
    float qx[2], qy[2], qz[2];
#pragma unroll
    for (int t = 0; t < 2; ++t) {
        int n = (j0 & 8191) + p + t * 16;
        qx[t] = p1[n]; qy[t] = p1[8192 + n]; qz[t] = p1[16384 + n];
    }
    u64 key[2][3];
#pragma unroll
    for (int t = 0; t < 2; ++t) { key[t][0] = 0; key[t][1] = 0; key[t][2] = 0; }

    for (int half = 0; half < 2; ++half) {
        int hbase = half * 1024;
        for (int i = tid; i < 1024; i += 256) {
            int s = hbase + i;
            float x = p2[s], y = p2[2048 + s], z = p2[4096 + s];
            pk[pkix(i)] = make_float4(x, y, z, -0.5f * (x * x + y * y + z * z));
        }
        __syncthreads();

        float g[2][3]; int id[2][3];
#pragma unroll
        for (int t = 0; t < 2; ++t) {
            g[t][0] = -3.4e38f; g[t][1] = -3.4e38f; g[t][2] = -3.4e38f;
            id[t][0] = 0; id[t][1] = 0; id[t][2] = 0;
        }
        int sb = ck * 64;
        const float4* pc = pk + pkix(sb);
#pragma unroll 2
        for (int it = 0; it < 64; ++it) {
            float4 cd = pc[it];
            int s = sb + it;
#pragma unroll
            for (int t = 0; t < 2; ++t) {
                float tv = fmaf(qx[t], cd.x, fmaf(qy[t], cd.y, fmaf(qz[t], cd.z, cd.w)));
                bool c0 = tv > g[t][0], c1 = tv > g[t][1], c2 = tv > g[t][2];
                float o0 = g[t][0], o1 = g[t][1];
                g[t][2] = __builtin_amdgcn_fmed3f(tv, o1, g[t][2]);
                g[t][1] = __builtin_amdgcn_fmed3f(tv, o0, o1);
                g[t][0] = fmaxf(o0, tv);
                id[t][2] = c1 ? id[t][1] : (c2 ? s : id[t][2]);
                id[t][1] = c0 ? id[t][0] : (c1 ? s : id[t][1]);
                id[t][0] = c0 ? s : id[t][0];
            }
        }
        __syncthreads();   // reads done before next half restages

#pragma unroll
        for (int t = 0; t < 2; ++t) {
#pragma unroll
            for (int r = 0; r < 3; ++r)
                ins3(((u64)fmono(g[t][r]) << 32) | (u64)(2047 - (hbase + id[t][r])),
                     key[t][0], key[t][1], key[t][2]);
        }
    }

    // in-wave merge across the 4 chunk-groups (lane>>4)
#pragma unroll
    for (int mask = 16; mask <= 32; mask <<= 1) {
#pragma unroll
        for (int t = 0; t < 2; ++t) {
            u64 m0 = shfl_xor_u64(key[t][0], mask);
            u64 m1 = shfl_xor_u64(key[t][1], mask);
            u64 m2 = shfl_xor_u64(key[t][2], mask);
            ins3(m0, key[t][0], key[t][1], key[t][2]);
            ins3(m1, key[t][0], key[t][1], key[t][2]);
            ins3(m2, key[t][0], key[t][1], key[t][2]);
        }
    }
    if (lane < 16) {
        u64* wr = &warr[(wv * 16 + p) * 6];
#pragma unroll
        for (int t = 0; t < 2; ++t) {
            wr[t * 3 + 0] = key[t][0]; wr[t * 3 + 1] = key[t][1]; wr[t * 3 + 2] = key[t][2];
        }
    }
    __syncthreads();
    if (tid < 32) {
        int pp = tid & 15, t = tid >> 4;
        const u64* w0 = &warr[pp * 6 + t * 3];
        u64 k0 = w0[0], k1 = w0[1], k2 = w0[2];
#pragma unroll
        for (int w = 1; w < 4; ++w) {
            const u64* wr = &warr[(w * 16 + pp) * 6 + t * 3];
            ins3(wr[0], k0, k1, k2);
            ins3(wr[1], k0, k1, k2);
            ins3(wr[2], k0, k1, k2);
        }
        int s0 = 2047 - (int)(k0 & 0xFFFFFFFFu);
        int s1 = 2047 - (int)(k1 & 0xFFFFFFFFu);
        int s2 = 2047 - (int)(k2 & 0xFFFFFFFFu);
        int j = j0 + pp + t * 16;
        int n = j & 8191;
        float x1 = p1[n], y1 = p1[8192 + n], z1 = p1[16384 + n];
        float n1 = x1 * x1 + y1 * y1 + z1 * z1;
        float X0 = p2[s0], Y0 = p2[2048 + s0], Z0 = p2[4096 + s0];
        float X1 = p2[s1], Y1v = p2[2048 + s1], Z1 = p2[4096 + s1];
        float X2 = p2[s2], Y2v = p2[2048 + s2], Z2 = p2[4096 + s2];
        float t0 = x1 * X0 + y1 * Y0 + z1 * Z0 - 0.5f * (X0 * X0 + Y0 * Y0 + Z0 * Z0);
        float t1 = x1 * X1 + y1 * Y1v + z1 * Z1 - 0.5f * (X1 * X1 + Y1v * Y1v + Z1 * Z1);
        float t2 = x1 * X2 + y1 * Y2v + z1 * Z2 - 0.5f * (X2 * X2 + Y2v * Y2v + Z2 * Z2);
        float d0 = fmaxf(fmaf(-2.f, t0, n1), 1e-10f);
        float d1 = fmaxf(fmaf(-2.f, t1, n1), 1e-10f);
        float d2 = fmaxf(fmaf(-2.f, t2, n1), 1e-10f);
        float w0v = 1.f / d0, w1v = 1.f / d1, w2v = 1.f / d2;
        float inv = 1.f / (w0v + w1v + w2v);
        idx_out[j * 3] = s0; idx_out[j * 3 + 1] = s1; idx_out[j * 3 + 2] = s2;
        w_out[j * 3] = w0v * inv; w_out[j * 3 + 1] = w1v * inv; w_out[j * 3 + 2] = w2v * inv;
    }
}

// ---------- interp: gather 3 rows of F2T, weighted sum -> bf16 [32768][256] ----------
__global__ __launch_bounds__(256, 8) void interp_kernel(const u16* __restrict__ f2t,
                                                        const int* __restrict__ idx,
                                                        const float* __restrict__ wgt,
                                                        u16* __restrict__ out) {
    int tid = threadIdx.x;
    int j = blockIdx.x * 16 + (tid >> 4);        // 16 rows/block, 16 threads/row
    int c0 = (tid & 15) * 16;                    // 16 channels/thread
    int b = j >> 13;
    const u16* fb = f2t + (size_t)b * 2048 * 256;
    const u16* r0 = fb + (size_t)idx[j * 3 + 0] * 256 + c0;
    const u16* r1 = fb + (size_t)idx[j * 3 + 1] * 256 + c0;
    const u16* r2 = fb + (size_t)idx[j * 3 + 2] * 256 + c0;
    float w0 = wgt[j * 3 + 0], w1 = wgt[j * 3 + 1], w2 = wgt[j * 3 + 2];
    u16* ob = out + (size_t)j * 256 + c0;
#pragma unroll
    for (int cc = 0; cc < 2; ++cc) {
        u16x8 v0 = *(const u16x8*)(r0 + cc * 8);
        u16x8 v1 = *(const u16x8*)(r1 + cc * 8);
        u16x8 v2 = *(const u16x8*)(r2 + cc * 8);
        u16x8 o;
#pragma unroll
        for (int e = 0; e < 8; ++e)
            o[e] = f2b(w0 * b2f(v0[e]) + w1 * b2f(v1[e]) + w2 * b2f(v2[e]));
        *(u16x8*)(ob + cc * 8) = o;
    }
}

// ---------- GEMM1: Yb[j][m] = bf16(sum_k A[j][k]*Bw[m][k] + bias[m]) ----------
// BN1 stats: fixed-point i64 atomicAdd into S1[16][512], slice = blockIdx.x & 15.
// 16 slices cut same-address RMW serialization 512 -> 32 adds/address (R4: the
// single-array version serialized ~15us at the coherence point). Deterministic:
// integer adds commute; the final fold sums all 16 slices.
__global__ __launch_bounds__(256, 2) void gemm1_kernel(const u16* __restrict__ A1,
                                                       const u16* __restrict__ A2,
                                                       const u16* __restrict__ Bw,
                                                       const float* __restrict__ bias,
                                                       u16* __restrict__ Yb,
                                                       u64* __restrict__ S1) {
    __shared__ __align__(16) char smemA[36864];
    u16* Al = (u16*)smemA;                       // [128][64], k-loop (swizzled cols)
    u16* Bl = (u16*)(smemA + 16384);             // [128][64], k-loop (swizzled cols)
    u16* T  = (u16*)smemA;                       // [128][136] epilogue bounce (overlays Al/Bl)
    int tid = threadIdx.x;
    int lane = tid & 63, wv = tid >> 6;
    int j0 = blockIdx.x * 128, m0 = blockIdx.y * 128;
    int l15 = lane & 15, q = lane >> 4;
    int wj = (wv >> 1) * 64, wm = (wv & 1) * 64;
    f32x4 acc[4][4];
#pragma unroll
    for (int i = 0; i < 4; ++i)
#pragma unroll
        for (int jj = 0; jj < 4; ++jj) acc[i][jj] = (f32x4){0.f, 0.f, 0.f, 0.f};

    int rbase = wv * 32;
    int lrow = lane >> 3, lchunk = lane & 7;
    int schunk = lchunk ^ lrow;                  // swizzled chunk for staging
    const u16* Bg = Bw + (size_t)m0 * 384;

    for (int k0 = 0; k0 < 384; k0 += 64) {
#pragma unroll
        for (int qq = 0; qq < 4; ++qq) {
            int row = rbase + qq * 8;
            async_cp16(&Bl[row * 64], Bg + (size_t)(row + lrow) * 384 + k0 + schunk * 8);
        }
        const u16* src; int str;
        if (k0 < 256) { src = A1 + (size_t)j0 * 256 + k0;         str = 256; }
        else          { src = A2 + (size_t)j0 * 128 + (k0 - 256); str = 128; }
#pragma unroll
        for (int qq = 0; qq < 4; ++qq) {
            int row = rbase + qq * 8;
            async_cp16(&Al[row * 64], src + (size_t)(row + lrow) * str + schunk * 8);
        }
        __syncthreads();
#pragma unroll
        for (int ks = 0; ks < 2; ++ks) {
            bf16x8 af[4], bfr[4];
#pragma unroll
            for (int i = 0; i < 4; ++i) {
                int row = wj + i * 16 + l15;
                af[i] = *(const bf16x8*)&Al[row * 64 + ((ks * 4 + q) ^ (l15 & 7)) * 8];
            }
#pragma unroll
            for (int i = 0; i < 4; ++i) {
                int row = wm + i * 16 + l15;
                bfr[i] = *(const bf16x8*)&Bl[row * 64 + ((ks * 4 + q) ^ (l15 & 7)) * 8];
            }
#pragma unroll
            for (int i = 0; i < 4; ++i)
#pragma unroll
                for (int jj = 0; jj < 4; ++jj)
                    acc[i][jj] = __builtin_amdgcn_mfma_f32_16x16x32_bf16(af[i], bfr[jj],
                                                                         acc[i][jj], 0, 0, 0);
        }
        __syncthreads();
    }
    // epilogue: sliced fixed-point stat atomics + bf16 tile into LDS
    int sl = (blockIdx.x & (NSLICE - 1)) * 512;
#pragma unroll
    for (int jj = 0; jj < 4; ++jj) {
        int ml = wm + jj * 16 + l15;
        float bv = bias[m0 + ml];
        float s = 0.f, s2 = 0.f;
#pragma unroll
        for (int i = 0; i < 4; ++i) {
            int jl = wj + i * 16 + q * 4;
#pragma unroll
            for (int r = 0; r < 4; ++r) {
                float v = acc[i][jj][r] + bv;
                s += v; s2 += v * v;
                T[(jl + r) * 136 + ml] = f2b(v);
            }
        }
        s += __shfl_xor(s, 16); s += __shfl_xor(s, 32);
        s2 += __shfl_xor(s2, 16); s2 += __shfl_xor(s2, 32);
        if (q == 0) {
            atomicAdd(&S1[sl + m0 + ml], (u64)(long long)llrintf(s * FPSCALE));
            atomicAdd(&S1[sl + 256 + m0 + ml], (u64)(long long)llrintf(s2 * FPSCALE));
        }
    }
    __syncthreads();
#pragma unroll
    for (int it = 0; it < 8; ++it) {
        int jl = it * 16 + wv * 4 + q;
        u16x8 v = *(const u16x8*)&T[jl * 136 + l15 * 8];
        *(u16x8*)&Yb[(size_t)(j0 + jl) * 256 + m0 + l15 * 8] = v;
    }
}

// ---------- gemm2_fused: local BN1 fold -> fused GEMM2 -> ONE barrier -> BN2+store ----------
// Barrier: arrive = one relaxed RMW/block; poll = relaxed LOAD (no invalidates, no
// directory serialization); stats sliced 16x so the pre-barrier atomics don't backlog.
__device__ __forceinline__ void gridbar(int* cnt, int target) {
    __syncthreads();                 // vmcnt(0): this block's stat atomics completed
    if (threadIdx.x == 0) {
        __hip_atomic_fetch_add(cnt, 1, __ATOMIC_RELAXED, __HIP_MEMORY_SCOPE_AGENT);
        while (__hip_atomic_load(cnt, __ATOMIC_RELAXED, __HIP_MEMORY_SCOPE_AGENT) < target)
            __builtin_amdgcn_s_sleep(16);
        __atomic_signal_fence(__ATOMIC_SEQ_CST);   // compiler barrier only
    }
    __syncthreads();
}

__global__ __launch_bounds__(256, 2) void gemm2_fused(const u16* __restrict__ Y1,
                                                      const u16* __restrict__ Bw,
                                                      const float* __restrict__ bias,
                                                      const u64* __restrict__ S1,
                                                      const float* __restrict__ g1,
                                                      const float* __restrict__ be1,
                                                      u64* __restrict__ S2,
                                                      const float* __restrict__ g2,
                                                      const float* __restrict__ be2,
                                                      float* __restrict__ OUT,
                                                      int* __restrict__ BAR) {
    __shared__ __align__(16) char smemA[36864];
    u16* Al = (u16*)smemA;                       // [128][64]
    u16* Bl = (u16*)(smemA + 16384);             // [128][64]
    u16* T  = (u16*)smemA;                       // [128][136] bf16, TRANSPOSED: [m][j]
    float2* BNT = (float2*)(smemA + 34816);      // 256 x (scale, shift)
    int tid = threadIdx.x;
    int bid = blockIdx.x;
    int lane = tid & 63, wv = tid >> 6;
    int j0 = (bid >> 1) * 128, m0 = (bid & 1) * 128;
    int l15 = lane & 15, q = lane >> 4;
    int wj = (wv >> 1) * 64, wm = (wv & 1) * 64;

    // ---- phase 0: fold BN1 locally (S1 complete: written by the previous kernel) ----
    {
        long long su = 0, sq = 0;
#pragma unroll
        for (int r = 0; r < NSLICE; ++r) {
            su += (long long)S1[r * 512 + tid];
            sq += (long long)S1[r * 512 + 256 + tid];
        }
        float fs  = (float)su * FPINV;
        float fs2 = (float)sq * FPINV;
        const float inv = 1.f / 32768.f;
        float mean = fs * inv;
        float var = fs2 * inv - mean * mean;
        float a = g1[tid] * rsqrtf(var + 1e-5f);
        BNT[tid] = make_float2(a, be1[tid] - mean * a);
    }
    __syncthreads();

    // ---- phase 1: BN1-fused GEMM (KT=256, A=relu(bn1(Y1))) ----
    f32x4 acc[4][4];
#pragma unroll
    for (int i = 0; i < 4; ++i)
#pragma unroll
        for (int jj = 0; jj < 4; ++jj) acc[i][jj] = (f32x4){0.f, 0.f, 0.f, 0.f};

    int rbase = wv * 32;
    int lrow = lane >> 3, lchunk = lane & 7;
    int schunk = lchunk ^ lrow;
    const u16* Bg = Bw + (size_t)m0 * 256;

    for (int k0 = 0; k0 < 256; k0 += 64) {
#pragma unroll
        for (int qq = 0; qq < 4; ++qq) {
            int row = rbase + qq * 8;
            async_cp16(&Bl[row * 64], Bg + (size_t)(row + lrow) * 256 + k0 + schunk * 8);
        }
        int c = k0 + lchunk * 8;
        float2 bn[8];
#pragma unroll
        for (int e = 0; e < 8; ++e) bn[e] = BNT[c + e];
#pragma unroll
        for (int qq = 0; qq < 4; ++qq) {
            int row = rbase + qq * 8;
            u16x8 y = *(const u16x8*)&Y1[(size_t)(j0 + row + lrow) * 256 + c];
            u16x8 o;
#pragma unroll
            for (int e = 0; e < 8; ++e)
                o[e] = f2b(fmaxf(b2f(y[e]) * bn[e].x + bn[e].y, 0.f));
            *(u16x8*)&Al[(row + lrow) * 64 + schunk * 8] = o;
        }
        __syncthreads();
#pragma unroll
        for (int ks = 0; ks < 2; ++ks) {
            bf16x8 af[4], bfr[4];
#pragma unroll
            for (int i = 0; i < 4; ++i) {
                int row = wj + i * 16 + l15;
                af[i] = *(const bf16x8*)&Al[row * 64 + ((ks * 4 + q) ^ (l15 & 7)) * 8];
            }
#pragma unroll
            for (int i = 0; i < 4; ++i) {
                int row = wm + i * 16 + l15;
                bfr[i] = *(const bf16x8*)&Bl[row * 64 + ((ks * 4 + q) ^ (l15 & 7)) * 8];
            }
#pragma unroll
            for (int i = 0; i < 4; ++i)
#pragma unroll
                for (int jj = 0; jj < 4; ++jj)
                    acc[i][jj] = __builtin_amdgcn_mfma_f32_16x16x32_bf16(af[i], bfr[jj],
                                                                         acc[i][jj], 0, 0, 0);
        }
        __syncthreads();
    }

    // ---- phase 2: sliced stat atomics + bf16 tile into LDS TRANSPOSED [m][j] ----
    int sl2 = ((bid >> 1) & (NSLICE - 1)) * 512;
#pragma unroll
    for (int jj = 0; jj < 4; ++jj) {
        int ml = wm + jj * 16 + l15;
        float bv = bias[m0 + ml];
        float s = 0.f, s2 = 0.f;
#pragma unroll
        for (int i = 0; i < 4; ++i) {
            int jl = wj + i * 16 + q * 4;
#pragma unroll
            for (int r = 0; r < 4; ++r) {
                float v = acc[i][jj][r] + bv;
                s += v; s2 += v * v;
                T[ml * 136 + (jl + r)] = f2b(v);   // [m][j] for transposed store
            }
        }
        s += __shfl_xor(s, 16); s += __shfl_xor(s, 32);
        s2 += __shfl_xor(s2, 16); s2 += __shfl_xor(s2, 32);
        if (q == 0) {
            atomicAdd(&S2[sl2 + m0 + ml], (u64)(long long)llrintf(s * FPSCALE));
            atomicAdd(&S2[sl2 + 256 + m0 + ml], (u64)(long long)llrintf(s2 * FPSCALE));
        }
    }
    gridbar(BAR, 512);               // the ONE grid barrier

    // ---- phase 3: fold BN2 locally for this block's 128 channels ----
    if (tid < 128) {
        int c = m0 + tid;
        long long su = 0, sq = 0;
#pragma unroll
        for (int r = 0; r < NSLICE; ++r) {
            su += (long long)ld_agent_u64(&S2[r * 512 + c]);
            sq += (long long)ld_agent_u64(&S2[r * 512 + 256 + c]);
        }
        float fs  = (float)su * FPINV;
        float fs2 = (float)sq * FPINV;
        const float inv = 1.f / 32768.f;
        float mean = fs * inv;
        float var = fs2 * inv - mean * mean;
        float a = g2[c] * rsqrtf(var + 1e-5f);
        BNT[tid] = make_float2(a, be2[c] - mean * a);
    }
    __syncthreads();

    // ---- phase 4: BN2+ReLU from T, transposed store out[b][o][n] ----
    int ol8 = tid >> 5;              // 0..7
    int j4 = (tid & 31) * 4;         // 0..124
    int bb = j0 >> 13, n0 = j0 & 8191;
#pragma unroll
    for (int it = 0; it < 16; ++it) {
        int ol = it * 8 + ol8;
        float2 bn = BNT[ol];
        ushort4 h = *(const ushort4*)&T[ol * 136 + j4];
        float4 v;
        v.x = fmaxf(b2f(h.x) * bn.x + bn.y, 0.f);
        v.y = fmaxf(b2f(h.y) * bn.x + bn.y, 0.f);
        v.z = fmaxf(b2f(h.z) * bn.x + bn.y, 0.f);
        v.w = fmaxf(b2f(h.w) * bn.x + bn.y, 0.f);
        *(float4*)&OUT[(size_t)bb * 2097152 + (size_t)(m0 + ol) * 8192 + n0 + j4] = v;
    }
}

extern "C" void kernel_launch(void* const* d_in, const int* in_sizes, int n_in,
                              void* d_out, int out_size, void* d_ws, size_t ws_size,
                              hipStream_t stream) {
    const float* pos1 = (const float*)d_in[0];
    const float* pos2 = (const float*)d_in[1];
    const float* feature1 = (const float*)d_in[2];
    const float* feature2 = (const float*)d_in[3];
    const float* W1 = (const float*)d_in[4];
    const float* b1 = (const float*)d_in[5];
    const float* g1 = (const float*)d_in[6];
    const float* be1 = (const float*)d_in[7];
    const float* W2 = (const float*)d_in[8];
    const float* b2 = (const float*)d_in[9];
    const float* g2 = (const float*)d_in[10];
    const float* be2 = (const float*)d_in[11];

    char* ws = (char*)d_ws;
    int*    IDX   = (int*)(ws + 0);                 // 393216 B
    float*  WGT   = (float*)(ws + 393216);          // 393216 B
    u16*    W1B   = (u16*)(ws + 786432);            // 196608 B
    u16*    W2B   = (u16*)(ws + 983040);            // 131072 B (contiguous after W1B)
    u16*    F2T   = (u16*)(ws + 1118208);           // 4 MiB  [4][2048][256]
    u16*    F1T   = (u16*)(ws + 5312512);           // 8 MiB  [4][8192][128]
    u16*    Y1    = (u16*)(ws + 13701120);          // 16 MiB [32768][256]
    u16*    INTERP= (u16*)(ws + 30478336);          // 16 MiB [32768][256] bf16
    u64*    SSTAT = (u64*)(ws + 47255552);          // S1[16][512] | S2[16][512] | BAR
    u64*    S1    = SSTAT;
    u64*    S2    = SSTAT + NSLICE * 512;
    int*    BAR   = (int*)(SSTAT + 2 * NSLICE * 512);
    float*  OUT   = (float*)d_out;

    prep_kernel<<<NB_NN + NB_CVT + NB_T2 + NB_T1 + 1, 256, 0, stream>>>(
        W1, W2, W1B, feature2, F2T, feature1, F1T, pos1, pos2, IDX, WGT, SSTAT);
    interp_kernel<<<2048, 256, 0, stream>>>(F2T, IDX, WGT, INTERP);
    gemm1_kernel<<<dim3(256, 2), 256, 0, stream>>>(INTERP, F1T, W1B, b1, Y1, S1);
    gemm2_fused<<<512, 256, 0, stream>>>(Y1, W2B, b2, S1, g1, be1,
                                         S2, g2, be2, OUT, BAR);
}

// Round 6
// 183.221 us; speedup vs baseline: 4.4023x; 1.0283x over previous
//
#include <hip/hip_runtime.h>
#include <hip/hip_bf16.h>
#include <cstdint>

typedef unsigned short u16;
typedef unsigned int u32;
typedef unsigned long long u64;
typedef __bf16 bf16x8 __attribute__((ext_vector_type(8)));
typedef float f32x4 __attribute__((ext_vector_type(4)));
typedef u16 u16x8 __attribute__((ext_vector_type(8)));

#define FPSCALE 1048576.0f          // 2^20 fixed-point for BN stats
#define FPINV   (1.0f / 1048576.0f)
#define NSLICE 16                   // atomic-contention slices

// ---------- helpers ----------
__device__ __forceinline__ u16 f2b(float f) {          // fp32 -> bf16 RNE
    unsigned int u = __float_as_uint(f);
    u += 0x7fffu + ((u >> 16) & 1u);
    return (u16)(u >> 16);
}
__device__ __forceinline__ float b2f(u16 h) {
    return __uint_as_float(((unsigned int)h) << 16);
}
__device__ __forceinline__ void async_cp16(void* lds, const void* g) {
    __builtin_amdgcn_global_load_lds((const __attribute__((address_space(1))) void*)g,
                                     (__attribute__((address_space(3))) void*)lds, 16, 0, 0);
}
__device__ __forceinline__ u64 ld_agent_u64(const u64* p) {
    return __hip_atomic_load(p, __ATOMIC_RELAXED, __HIP_MEMORY_SCOPE_AGENT);
}
// monotone unsigned mapping of float bits (order-preserving, EXACT)
__device__ __forceinline__ u32 fmono(float f) {
    u32 u = __float_as_uint(f);
    return u ^ (((u32)((int)u >> 31)) | 0x80000000u);
}
__device__ __forceinline__ u64 shfl_xor_u64(u64 v, int mask) {
    u32 lo = (u32)v, hi = (u32)(v >> 32);
    lo = (u32)__shfl_xor((int)lo, mask);
    hi = (u32)__shfl_xor((int)hi, mask);
    return ((u64)hi << 32) | lo;
}
// insert exact key into descending top-3 (keys unique: idx field breaks ties)
__device__ __forceinline__ void ins3(u64 k, u64& k0, u64& k1, u64& k2) {
    bool c0 = k > k0, c1 = k > k1, c2 = k > k2;
    k2 = c1 ? k1 : (c2 ? k : k2);
    k1 = c0 ? k0 : (c1 ? k : k1);
    k0 = c0 ? k : k0;
}
// padded pk index: one float4 pad every 64 entries
__device__ __forceinline__ int pkix(int i) { return i + (i >> 6); }

// ================= prep kernel: three_nn FIRST, then cvt + transposes =================
// NN: 2048 blocks x 16 queries (R5: 1024x32 left occupancy at 40%); launch_bounds
// (256,8) -> LDS 18.2KB and VGPR 24 both allow 8 blocks/CU in the nn tail.
#define NB_NN  2048
#define NB_CVT 160
#define NB_T2  512
#define NB_T1  1024

__global__ __launch_bounds__(256, 8) void prep_kernel(const float* __restrict__ w1,
                                                      const float* __restrict__ w2,
                                                      u16* __restrict__ wb,
                                                      const float* __restrict__ feature2,
                                                      u16* __restrict__ f2t,
                                                      const float* __restrict__ feature1,
                                                      u16* __restrict__ f1t,
                                                      const float* __restrict__ pos1,
                                                      const float* __restrict__ pos2,
                                                      int* __restrict__ idx_out,
                                                      float* __restrict__ w_out,
                                                      u64* __restrict__ SZ) {
    __shared__ __align__(16) char smem[18176];   // 16640 pk-half + 1536 warr
    int bi = blockIdx.x;
    int tid = threadIdx.x;

    if (bi >= NB_NN) {
        int ci = bi - NB_NN;
        if (ci >= NB_CVT + NB_T2 + NB_T1) {
            // ---- zero stats: S1[16][512] | S2[16][512] | BAR (per graph replay) ----
            for (int i = tid; i < 2 * NSLICE * 512; i += 256) SZ[i] = 0;
            if (tid == 0) *(int*)(SZ + 2 * NSLICE * 512) = 0;
            return;
        }
        if (ci < NB_CVT) {
            int i = ci * 256 + tid;
            if (i < 40960) {
                const float* src = (i < 24576) ? w1 : w2;
                int k = (i < 24576) ? i : (i - 24576);
                float4 v = *(const float4*)&src[(size_t)k * 4];
                ushort4 o;
                o.x = f2b(v.x); o.y = f2b(v.y); o.z = f2b(v.z); o.w = f2b(v.w);
                *(ushort4*)&wb[(size_t)i * 4] = o;
            }
            return;
        }
        // ---- transpose [B][C][S] -> [B][S][C] bf16 ----
        float (*t)[65] = (float (*)[65])smem;
        const float* in; u16* out; int C, S, s0, c0, b;
        if (ci < NB_CVT + NB_T2) {
            int lin = ci - NB_CVT;
            C = 256; S = 2048; in = feature2; out = f2t;
            s0 = (lin & 31) * 64; c0 = ((lin >> 5) & 3) * 64; b = lin >> 7;
        } else {
            int lin = ci - NB_CVT - NB_T2;
            C = 128; S = 8192; in = feature1; out = f1t;
            s0 = (lin & 127) * 64; c0 = ((lin >> 7) & 1) * 64; b = lin >> 8;
        }
        const float* ib = in + (size_t)b * C * S;
        u16* ob = out + (size_t)b * S * C;
        int col = tid & 63, r0 = tid >> 6;
#pragma unroll
        for (int p = 0; p < 16; ++p) {
            int c = p * 4 + r0;
            t[c][col] = ib[(size_t)(c0 + c) * S + s0 + col];
        }
        __syncthreads();
#pragma unroll
        for (int p = 0; p < 16; ++p) {
            int s = p * 4 + r0;
            ob[(size_t)(s0 + s) * C + c0 + col] = f2b(t[col][s]);
        }
        return;
    }

    // ---- three_nn: 16 queries/block; thread handles ONE query ----
    float4* pk = (float4*)smem;                          // padded: 1040 float4 = 16640 B
    u64* warr = (u64*)(smem + 16640);                    // [4 waves][16 p][3]
    int j0 = bi * 16;
    int b = j0 >> 13;
    const float* p2 = pos2 + (size_t)b * 3 * 2048;
    int p = tid & 15, ck = tid >> 4;
    int wv = tid >> 6, lane = tid & 63;
    const float* p1 = pos1 + (size_t)b * 3 * 8192;
    int n = (j0 & 8191) + p;
    float qx = p1[n], qy = p1[8192 + n], qz = p1[16384 + n];
    u64 key0 = 0, key1 = 0, key2 = 0;

    for (int half = 0; half < 2; ++half) {
        int hbase = half * 1024;
        for (int i = tid; i < 1024; i += 256) {
            int s = hbase + i;
            float x = p2[s], y = p2[2048 + s], z = p2[4096 + s];
            pk[pkix(i)] = make_float4(x, y, z, -0.5f * (x * x + y * y + z * z));
        }
        __syncthreads();

        float g0 = -3.4e38f, g1 = -3.4e38f, g2 = -3.4e38f;
        int id0 = 0, id1 = 0, id2 = 0;
        int sb = ck * 64;
        const float4* pc = pk + pkix(sb);
#pragma unroll 4
        for (int it = 0; it < 64; ++it) {
            float4 cd = pc[it];
            int s = sb + it;
            float tv = fmaf(qx, cd.x, fmaf(qy, cd.y, fmaf(qz, cd.z, cd.w)));
            bool c0 = tv > g0, c1 = tv > g1, c2 = tv > g2;
            float o0 = g0, o1 = g1;
            g2 = __builtin_amdgcn_fmed3f(tv, o1, g2);
            g1 = __builtin_amdgcn_fmed3f(tv, o0, o1);
            g0 = fmaxf(o0, tv);
            id2 = c1 ? id1 : (c2 ? s : id2);
            id1 = c0 ? id0 : (c1 ? s : id1);
            id0 = c0 ? s : id0;
        }
        __syncthreads();   // reads done before next half restages

        ins3(((u64)fmono(g0) << 32) | (u64)(2047 - (hbase + id0)), key0, key1, key2);
        ins3(((u64)fmono(g1) << 32) | (u64)(2047 - (hbase + id1)), key0, key1, key2);
        ins3(((u64)fmono(g2) << 32) | (u64)(2047 - (hbase + id2)), key0, key1, key2);
    }

    // in-wave merge across the 4 chunk-groups (lane>>4)
#pragma unroll
    for (int mask = 16; mask <= 32; mask <<= 1) {
        u64 m0 = shfl_xor_u64(key0, mask);
        u64 m1 = shfl_xor_u64(key1, mask);
        u64 m2 = shfl_xor_u64(key2, mask);
        ins3(m0, key0, key1, key2);
        ins3(m1, key0, key1, key2);
        ins3(m2, key0, key1, key2);
    }
    if (lane < 16) {
        u64* wr = &warr[(wv * 16 + p) * 3];
        wr[0] = key0; wr[1] = key1; wr[2] = key2;
    }
    __syncthreads();
    if (tid < 16) {
        int pp = tid;
        const u64* w0 = &warr[pp * 3];
        u64 k0 = w0[0], k1 = w0[1], k2 = w0[2];
#pragma unroll
        for (int w = 1; w < 4; ++w) {
            const u64* wr = &warr[(w * 16 + pp) * 3];
            ins3(wr[0], k0, k1, k2);
            ins3(wr[1], k0, k1, k2);
            ins3(wr[2], k0, k1, k2);
        }
        int s0 = 2047 - (int)(k0 & 0xFFFFFFFFu);
        int s1 = 2047 - (int)(k1 & 0xFFFFFFFFu);
        int s2 = 2047 - (int)(k2 & 0xFFFFFFFFu);
        int j = j0 + pp;
        int nn = j & 8191;
        float x1 = p1[nn], y1 = p1[8192 + nn], z1 = p1[16384 + nn];
        float n1 = x1 * x1 + y1 * y1 + z1 * z1;
        float X0 = p2[s0], Y0 = p2[2048 + s0], Z0 = p2[4096 + s0];
        float X1 = p2[s1], Y1v = p2[2048 + s1], Z1 = p2[4096 + s1];
        float X2 = p2[s2], Y2v = p2[2048 + s2], Z2 = p2[4096 + s2];
        float t0 = x1 * X0 + y1 * Y0 + z1 * Z0 - 0.5f * (X0 * X0 + Y0 * Y0 + Z0 * Z0);
        float t1 = x1 * X1 + y1 * Y1v + z1 * Z1 - 0.5f * (X1 * X1 + Y1v * Y1v + Z1 * Z1);
        float t2 = x1 * X2 + y1 * Y2v + z1 * Z2 - 0.5f * (X2 * X2 + Y2v * Y2v + Z2 * Z2);
        float d0 = fmaxf(fmaf(-2.f, t0, n1), 1e-10f);
        float d1 = fmaxf(fmaf(-2.f, t1, n1), 1e-10f);
        float d2 = fmaxf(fmaf(-2.f, t2, n1), 1e-10f);
        float w0v = 1.f / d0, w1v = 1.f / d1, w2v = 1.f / d2;
        float inv = 1.f / (w0v + w1v + w2v);
        idx_out[j * 3] = s0; idx_out[j * 3 + 1] = s1; idx_out[j * 3 + 2] = s2;
        w_out[j * 3] = w0v * inv; w_out[j * 3 + 1] = w1v * inv; w_out[j * 3 + 2] = w2v * inv;
    }
}

// ---------- interp: gather 3 rows of F2T, weighted sum -> bf16 [32768][256] ----------
__global__ __launch_bounds__(256, 8) void interp_kernel(const u16* __restrict__ f2t,
                                                        const int* __restrict__ idx,
                                                        const float* __restrict__ wgt,
                                                        u16* __restrict__ out) {
    int tid = threadIdx.x;
    int j = blockIdx.x * 16 + (tid >> 4);        // 16 rows/block, 16 threads/row
    int c0 = (tid & 15) * 16;                    // 16 channels/thread
    int b = j >> 13;
    const u16* fb = f2t + (size_t)b * 2048 * 256;
    const u16* r0 = fb + (size_t)idx[j * 3 + 0] * 256 + c0;
    const u16* r1 = fb + (size_t)idx[j * 3 + 1] * 256 + c0;
    const u16* r2 = fb + (size_t)idx[j * 3 + 2] * 256 + c0;
    float w0 = wgt[j * 3 + 0], w1 = wgt[j * 3 + 1], w2 = wgt[j * 3 + 2];
    u16* ob = out + (size_t)j * 256 + c0;
#pragma unroll
    for (int cc = 0; cc < 2; ++cc) {
        u16x8 v0 = *(const u16x8*)(r0 + cc * 8);
        u16x8 v1 = *(const u16x8*)(r1 + cc * 8);
        u16x8 v2 = *(const u16x8*)(r2 + cc * 8);
        u16x8 o;
#pragma unroll
        for (int e = 0; e < 8; ++e)
            o[e] = f2b(w0 * b2f(v0[e]) + w1 * b2f(v1[e]) + w2 * b2f(v2[e]));
        *(u16x8*)(ob + cc * 8) = o;
    }
}

// ================= mlp_fused: GEMM1 -> BN1 -> GEMM2 -> BN2 -> out, ONE kernel =================
// 256 blocks, each owns a FULL 128-row slab: Y1 lives in registers (acc[2][16] f32x4),
// never in HBM. LDS 96KB -> exactly 1 block/CU -> all 256 blocks resident (barrier safe).
// Barriers: proven R5 pattern (arrive=relaxed RMW, poll=relaxed load, s_sleep).
// Numerics: identical op chain to the R5 two-kernel version (same MFMA order, same
// f2b/b2f rounding points); only fp32 stat partial-sum grouping differs (ulp-level).
__device__ __forceinline__ void gridbar(int* cnt, int target) {
    __syncthreads();                 // drain this block's stat atomics (vmcnt 0)
    if (threadIdx.x == 0) {
        __hip_atomic_fetch_add(cnt, 1, __ATOMIC_RELAXED, __HIP_MEMORY_SCOPE_AGENT);
        while (__hip_atomic_load(cnt, __ATOMIC_RELAXED, __HIP_MEMORY_SCOPE_AGENT) < target)
            __builtin_amdgcn_s_sleep(16);
        __atomic_signal_fence(__ATOMIC_SEQ_CST);   // compiler barrier only
    }
    __syncthreads();
}

__global__ __launch_bounds__(256, 1) void mlp_fused(const u16* __restrict__ A1,   // INTERP
                                                    const u16* __restrict__ A2g,  // F1T
                                                    const u16* __restrict__ W1b,
                                                    const float* __restrict__ b1,
                                                    const u16* __restrict__ W2b,
                                                    const float* __restrict__ b2,
                                                    u64* __restrict__ S1,
                                                    const float* __restrict__ g1,
                                                    const float* __restrict__ be1,
                                                    u64* __restrict__ S2,
                                                    const float* __restrict__ g2,
                                                    const float* __restrict__ be2,
                                                    float* __restrict__ OUT,
                                                    int* __restrict__ BAR) {
    __shared__ __align__(16) char smem[98304];
    u16* AS  = (u16*)smem;                     // phase A: A-stage [128][64]  (16 KB)
    u16* BS  = (u16*)(smem + 16384);           // phase A: B-stage [256][64]  (32 KB)
    u16* A2  = (u16*)smem;                     // phase B: A tile  [128][256] (64 KB)
    u16* BS2 = (u16*)(smem + 65536);           // phase B: B-stage [256][64]  (32 KB)
    float* SC  = (float*)(smem + 65536);       // stats scratch [4][256]
    float* SC2 = (float*)(smem + 65536 + 4096);
    float2* BNT = (float2*)(smem + 65536);     // BN fold table (after SC consumed)

    int tid = threadIdx.x, bid = blockIdx.x;
    int lane = tid & 63, wv = tid >> 6;
    int l15 = lane & 15, q = lane >> 4;
    int lrow = lane >> 3, lchunk = lane & 7, schunk = lchunk ^ lrow;
    int j0 = bid * 128;
    int wrow = wv * 32;
    int sl = (bid & (NSLICE - 1)) * 512;

    f32x4 acc[2][16];
#pragma unroll
    for (int i = 0; i < 2; ++i)
#pragma unroll
        for (int jj = 0; jj < 16; ++jj) acc[i][jj] = (f32x4){0.f, 0.f, 0.f, 0.f};

    // ---------------- phase A: Y1 = A[128][384] x W1^T -> acc ----------------
    for (int k0 = 0; k0 < 384; k0 += 64) {
#pragma unroll
        for (int qq = 0; qq < 8; ++qq) {       // B: 256 rows
            int row = wv * 64 + qq * 8;
            async_cp16(&BS[row * 64], W1b + (size_t)(row + lrow) * 384 + k0 + schunk * 8);
        }
        const u16* src; int str;
        if (k0 < 256) { src = A1 + (size_t)j0 * 256 + k0;          str = 256; }
        else          { src = A2g + (size_t)j0 * 128 + (k0 - 256); str = 128; }
#pragma unroll
        for (int qq = 0; qq < 4; ++qq) {       // A: 128 rows
            int row = wv * 32 + qq * 8;
            async_cp16(&AS[row * 64], src + (size_t)(row + lrow) * str + schunk * 8);
        }
        __syncthreads();
#pragma unroll
        for (int ks = 0; ks < 2; ++ks) {
            bf16x8 af[2];
#pragma unroll
            for (int i = 0; i < 2; ++i) {
                int row = wrow + i * 16 + l15;
                af[i] = *(const bf16x8*)&AS[row * 64 + ((ks * 4 + q) ^ (l15 & 7)) * 8];
            }
#pragma unroll
            for (int jj = 0; jj < 16; ++jj) {
                int row = jj * 16 + l15;
                bf16x8 bfr = *(const bf16x8*)&BS[row * 64 + ((ks * 4 + q) ^ (l15 & 7)) * 8];
#pragma unroll
                for (int i = 0; i < 2; ++i)
                    acc[i][jj] = __builtin_amdgcn_mfma_f32_16x16x32_bf16(af[i], bfr,
                                                                         acc[i][jj], 0, 0, 0);
            }
        }
        __syncthreads();
    }

    // ---- epilogue A: bias + per-channel stats (LDS cross-wave reduce, sliced atomics) ----
#pragma unroll
    for (int jj = 0; jj < 16; ++jj) {
        float bv = b1[jj * 16 + l15];
        float s = 0.f, s2 = 0.f;
#pragma unroll
        for (int i = 0; i < 2; ++i)
#pragma unroll
            for (int r = 0; r < 4; ++r) {
                acc[i][jj][r] += bv;
                float v = acc[i][jj][r];
                s += v; s2 += v * v;
            }
        s += __shfl_xor(s, 16); s += __shfl_xor(s, 32);
        s2 += __shfl_xor(s2, 16); s2 += __shfl_xor(s2, 32);
        if (q == 0) {
            SC[wv * 256 + jj * 16 + l15] = s;
            SC2[wv * 256 + jj * 16 + l15] = s2;
        }
    }
    __syncthreads();
    {
        float fs = SC[tid] + SC[256 + tid] + SC[512 + tid] + SC[768 + tid];
        float fs2 = SC2[tid] + SC2[256 + tid] + SC2[512 + tid] + SC2[768 + tid];
        atomicAdd(&S1[sl + tid], (u64)(long long)llrintf(fs * FPSCALE));
        atomicAdd(&S1[sl + 256 + tid], (u64)(long long)llrintf(fs2 * FPSCALE));
    }
    gridbar(BAR, 256);

    // ---- BN1 fold (all 256 channels; ld_agent: atomics wrote at LLC) ----
    {
        long long su = 0, sq = 0;
#pragma unroll
        for (int r = 0; r < NSLICE; ++r) {
            su += (long long)ld_agent_u64(&S1[r * 512 + tid]);
            sq += (long long)ld_agent_u64(&S1[r * 512 + 256 + tid]);
        }
        float fs = (float)su * FPINV;
        float fs2 = (float)sq * FPINV;
        const float inv = 1.f / 32768.f;
        float mean = fs * inv;
        float var = fs2 * inv - mean * mean;
        float a = g1[tid] * rsqrtf(var + 1e-5f);
        BNT[tid] = make_float2(a, be1[tid] - mean * a);
    }
    __syncthreads();

    // ---- build A2 tile in LDS: relu(bn1(bf16(Y1))) , swizzled for MFMA reads ----
#pragma unroll
    for (int i = 0; i < 2; ++i)
#pragma unroll
        for (int jj = 0; jj < 16; ++jj) {
            int c = jj * 16 + l15;
            float2 bn = BNT[c];
            int chunkbase = c >> 3;            // jj*2 + (l15>>3)
            int win = c & 7;
#pragma unroll
            for (int r = 0; r < 4; ++r) {
                int row = wrow + i * 16 + q * 4 + r;
                float vb = b2f(f2b(acc[i][jj][r]));           // bf16 round = old Y1 store
                u16 h = f2b(fmaxf(vb * bn.x + bn.y, 0.f));
                A2[row * 256 + ((chunkbase ^ (row & 7)) * 8 + win)] = h;
            }
        }
    __syncthreads();                            // A2 done; BNT/SC region now dead

    // ---------------- phase B: Y2 = A2[128][256] x W2^T -> acc ----------------
#pragma unroll
    for (int i = 0; i < 2; ++i)
#pragma unroll
        for (int jj = 0; jj < 16; ++jj) acc[i][jj] = (f32x4){0.f, 0.f, 0.f, 0.f};

    for (int kstep = 0; kstep < 4; ++kstep) {
        int k0 = kstep * 64;
#pragma unroll
        for (int qq = 0; qq < 8; ++qq) {
            int row = wv * 64 + qq * 8;
            async_cp16(&BS2[row * 64], W2b + (size_t)(row + lrow) * 256 + k0 + schunk * 8);
        }
        __syncthreads();
#pragma unroll
        for (int ks = 0; ks < 2; ++ks) {
            bf16x8 af[2];
#pragma unroll
            for (int i = 0; i < 2; ++i) {
                int row = wrow + i * 16 + l15;
                int kc = kstep * 8 + ks * 4 + q;
                af[i] = *(const bf16x8*)&A2[row * 256 + ((kc ^ (row & 7)) * 8)];
            }
#pragma unroll
            for (int jj = 0; jj < 16; ++jj) {
                int row = jj * 16 + l15;
                bf16x8 bfr = *(const bf16x8*)&BS2[row * 64 + ((ks * 4 + q) ^ (l15 & 7)) * 8];
#pragma unroll
                for (int i = 0; i < 2; ++i)
                    acc[i][jj] = __builtin_amdgcn_mfma_f32_16x16x32_bf16(af[i], bfr,
                                                                         acc[i][jj], 0, 0, 0);
            }
        }
        __syncthreads();
    }

    // ---- epilogue B: bias + stats ----
#pragma unroll
    for (int jj = 0; jj < 16; ++jj) {
        float bv = b2[jj * 16 + l15];
        float s = 0.f, s2 = 0.f;
#pragma unroll
        for (int i = 0; i < 2; ++i)
#pragma unroll
            for (int r = 0; r < 4; ++r) {
                acc[i][jj][r] += bv;
                float v = acc[i][jj][r];
                s += v; s2 += v * v;
            }
        s += __shfl_xor(s, 16); s += __shfl_xor(s, 32);
        s2 += __shfl_xor(s2, 16); s2 += __shfl_xor(s2, 32);
        if (q == 0) {
            SC[wv * 256 + jj * 16 + l15] = s;
            SC2[wv * 256 + jj * 16 + l15] = s2;
        }
    }
    __syncthreads();
    {
        float fs = SC[tid] + SC[256 + tid] + SC[512 + tid] + SC[768 + tid];
        float fs2 = SC2[tid] + SC2[256 + tid] + SC2[512 + tid] + SC2[768 + tid];
        atomicAdd(&S2[sl + tid], (u64)(long long)llrintf(fs * FPSCALE));
        atomicAdd(&S2[sl + 256 + tid], (u64)(long long)llrintf(fs2 * FPSCALE));
    }
    gridbar(BAR, 512);

    // ---- BN2 fold ----
    {
        long long su = 0, sq = 0;
#pragma unroll
        for (int r = 0; r < NSLICE; ++r) {
            su += (long long)ld_agent_u64(&S2[r * 512 + tid]);
            sq += (long long)ld_agent_u64(&S2[r * 512 + 256 + tid]);
        }
        float fs = (float)su * FPINV;
        float fs2 = (float)sq * FPINV;
        const float inv = 1.f / 32768.f;
        float mean = fs * inv;
        float var = fs2 * inv - mean * mean;
        float a = g2[tid] * rsqrtf(var + 1e-5f);
        BNT[tid] = make_float2(a, be2[tid] - mean * a);
    }
    __syncthreads();

    // ---- store: out[b][o][n] = relu(bn2(bf16(Y2))) straight from registers ----
    int bb = j0 >> 13, nbase = j0 & 8191;
#pragma unroll
    for (int i = 0; i < 2; ++i)
#pragma unroll
        for (int jj = 0; jj < 16; ++jj) {
            int o = jj * 16 + l15;
            float2 bn = BNT[o];
            int n0 = nbase + wrow + i * 16 + q * 4;
            float4 v;
            v.x = fmaxf(b2f(f2b(acc[i][jj][0])) * bn.x + bn.y, 0.f);
            v.y = fmaxf(b2f(f2b(acc[i][jj][1])) * bn.x + bn.y, 0.f);
            v.z = fmaxf(b2f(f2b(acc[i][jj][2])) * bn.x + bn.y, 0.f);
            v.w = fmaxf(b2f(f2b(acc[i][jj][3])) * bn.x + bn.y, 0.f);
            *(float4*)&OUT[(size_t)bb * 2097152 + (size_t)o * 8192 + n0] = v;
        }
}

extern "C" void kernel_launch(void* const* d_in, const int* in_sizes, int n_in,
                              void* d_out, int out_size, void* d_ws, size_t ws_size,
                              hipStream_t stream) {
    const float* pos1 = (const float*)d_in[0];
    const float* pos2 = (const float*)d_in[1];
    const float* feature1 = (const float*)d_in[2];
    const float* feature2 = (const float*)d_in[3];
    const float* W1 = (const float*)d_in[4];
    const float* b1 = (const float*)d_in[5];
    const float* g1 = (const float*)d_in[6];
    const float* be1 = (const float*)d_in[7];
    const float* W2 = (const float*)d_in[8];
    const float* b2 = (const float*)d_in[9];
    const float* g2 = (const float*)d_in[10];
    const float* be2 = (const float*)d_in[11];

    char* ws = (char*)d_ws;
    int*    IDX   = (int*)(ws + 0);                 // 393216 B
    float*  WGT   = (float*)(ws + 393216);          // 393216 B
    u16*    W1B   = (u16*)(ws + 786432);            // 196608 B
    u16*    W2B   = (u16*)(ws + 983040);            // 131072 B
    u16*    F2T   = (u16*)(ws + 1118208);           // 4 MiB  [4][2048][256]
    u16*    F1T   = (u16*)(ws + 5312512);           // 8 MiB  [4][8192][128]
    u16*    INTERP= (u16*)(ws + 30478336);          // 16 MiB [32768][256] bf16
    u64*    SSTAT = (u64*)(ws + 47255552);          // S1[16][512] | S2[16][512] | BAR
    u64*    S1    = SSTAT;
    u64*    S2    = SSTAT + NSLICE * 512;
    int*    BAR   = (int*)(SSTAT + 2 * NSLICE * 512);
    float*  OUT   = (float*)d_out;

    prep_kernel<<<NB_NN + NB_CVT + NB_T2 + NB_T1 + 1, 256, 0, stream>>>(
        W1, W2, W1B, feature2, F2T, feature1, F1T, pos1, pos2, IDX, WGT, SSTAT);
    interp_kernel<<<2048, 256, 0, stream>>>(F2T, IDX, WGT, INTERP);
    mlp_fused<<<256, 256, 0, stream>>>(INTERP, F1T, W1B, b1, W2B, b2,
                                       S1, g1, be1, S2, g2, be2, OUT, BAR);
}